// Round 4
// baseline (1042.395 us; speedup 1.0000x reference)
//
#include <hip/hip_runtime.h>
#include <stddef.h>

#define EPS 1e-5f
#define N_HW 3136              // 56*56
#define G 16                   // batches per group (2 groups of 16)
#define NG (G * N_HW)          // 50176 = group GEMM N dimension
#define DIMC 800

// ---------------- ws layout (bytes), single group (groups run sequentially) ----
// H   : fp32 [800][G][3136] = 160,563,200
// XA0 : fp32 [ 32][G][3136] =   6,422,528  @ 160,563,200
// m4/meanH: 192*G floats each; opre: G*192 floats
static const size_t XA0_OFF = (size_t)DIMC * NG * 4;           // 160,563,200
static const size_t M4_OFF  = XA0_OFF + (size_t)32 * NG * 4;   // 166,985,728
static const size_t MH_OFF  = M4_OFF + 192 * G * 4;
static const size_t OP_OFF  = MH_OFF + 192 * G * 4;
static const size_t NEED    = OP_OFF + (size_t)G * 192 * 4;    // 167,022,592

// ---------------- stem ----------------
__global__ __launch_bounds__(256) void stem_conv1(
    const float* __restrict__ xg, const float* __restrict__ w, const float* __restrict__ b1,
    const float* __restrict__ g, const float* __restrict__ bb,
    const float* __restrict__ m, const float* __restrict__ v,
    float* __restrict__ h1) {
  int idx = blockIdx.x * 256 + threadIdx.x;       // ((c*G)+bg)*12544 + p
  int p = idx % 12544;
  int t = idx / 12544;
  int bg = t & (G - 1);
  int c = t >> 4;
  int oy = p / 112, ox = p % 112;
  float acc = b1[c];
  for (int ci = 0; ci < 3; ci++) {
    const float* xp = xg + ((size_t)(bg * 3 + ci)) * 224 * 224;
    const float* wp = w + (c * 3 + ci) * 9;
#pragma unroll
    for (int ky = 0; ky < 3; ky++) {
      int iy = oy * 2 - 1 + ky;
      if (iy < 0 || iy >= 224) continue;
#pragma unroll
      for (int kx = 0; kx < 3; kx++) {
        int ix = ox * 2 - 1 + kx;
        if (ix < 0 || ix >= 224) continue;
        acc += xp[iy * 224 + ix] * wp[ky * 3 + kx];
      }
    }
  }
  float y = (acc - m[c]) * (g[c] * rsqrtf(v[c] + EPS)) + bb[c];
  h1[idx] = fmaxf(y, 0.f);
}

__global__ __launch_bounds__(256) void stem_dw(
    const float* __restrict__ h1, const float* __restrict__ dw, const float* __restrict__ dwb,
    float* __restrict__ h2) {
  int idx = blockIdx.x * 256 + threadIdx.x;       // ((c*G)+bg)*3136 + q
  int q = idx % N_HW;
  int t = idx / N_HW;
  int bg = t & (G - 1);
  int c = t >> 4;
  int qy = q / 56, qx = q % 56;
  const float* plane = h1 + (size_t)(c * G + bg) * 12544;
  float acc = dwb[c];
#pragma unroll
  for (int ky = 0; ky < 3; ky++) {
    int iy = qy * 2 - 1 + ky;
    if (iy < 0 || iy >= 112) continue;
#pragma unroll
    for (int kx = 0; kx < 3; kx++) {
      int ix = qx * 2 - 1 + kx;
      if (ix < 0 || ix >= 112) continue;
      acc += plane[iy * 112 + ix] * dw[c * 9 + ky * 3 + kx];
    }
  }
  h2[idx] = acc;
}

__global__ __launch_bounds__(256) void stem_pw(
    const float* __restrict__ h2, const float* __restrict__ w2, const float* __restrict__ b2,
    const float* __restrict__ g, const float* __restrict__ bb,
    const float* __restrict__ m, const float* __restrict__ v,
    float* __restrict__ H) {
  int idx = blockIdx.x * 256 + threadIdx.x;       // ((o*G)+bg)*3136 + q
  int q = idx % N_HW;
  int t = idx / N_HW;
  int bg = t & (G - 1);
  int o = t >> 4;
  float acc = b2[o];
#pragma unroll
  for (int c = 0; c < 16; c++) acc += w2[o * 16 + c] * h2[(size_t)(c * G + bg) * N_HW + q];
  float y = (acc - m[o]) * (g[o] * rsqrtf(v[o] + EPS)) + bb[o];
  H[idx] = y;
}

// ------- fused instance-norm stats + norm + relu + depthwise 3x3 (pad 1) -------
// base pre-offset to channel r0 (pitch NG); cdw/gamma/beta indexed at cdwoff+cl.
// XA may alias base (exact per-block self-overlay at layer 1): no __restrict__.
__global__ __launch_bounds__(256) void dw_fused(
    const float* base, const float* __restrict__ cdw,
    const float* __restrict__ in_g, const float* __restrict__ in_b,
    float* XA, int cdwoff) {
  __shared__ float sm[58 * 58];
  __shared__ float red[256], red2[256];
  __shared__ float ssc, ssh;
  int blk = blockIdx.x;            // cl*G + bg
  int cl = blk >> 4;
  int c = cdwoff + cl;
  int tid = threadIdx.x;
  for (int i = tid; i < 58 * 58; i += 256) sm[i] = 0.f;
  __syncthreads();
  const float* row = base + (size_t)blk * N_HW;
  float s = 0.f, s2 = 0.f;
  for (int i = tid; i < N_HW; i += 256) {
    float xv = row[i];
    s += xv; s2 += xv * xv;
    int y = i / 56, x = i % 56;
    sm[(y + 1) * 58 + x + 1] = xv;
  }
  red[tid] = s; red2[tid] = s2;
  __syncthreads();
  for (int o = 128; o > 0; o >>= 1) {
    if (tid < o) { red[tid] += red[tid + o]; red2[tid] += red2[tid + o]; }
    __syncthreads();
  }
  if (tid == 0) {
    float mean = red[0] * (1.f / N_HW);
    float var = fmaxf(red2[0] * (1.f / N_HW) - mean * mean, 0.f);
    float sc = in_g[c] * rsqrtf(var + EPS);
    ssc = sc; ssh = in_b[c] - mean * sc;
  }
  __syncthreads();
  float sc = ssc, sh = ssh;
  for (int i = tid; i < N_HW; i += 256) {
    int y = i / 56, x = i % 56;
    int pos = (y + 1) * 58 + x + 1;
    sm[pos] = fmaxf(sm[pos] * sc + sh, 0.f);
  }
  __syncthreads();
  float w0 = cdw[c * 9 + 0], w1 = cdw[c * 9 + 1], w2 = cdw[c * 9 + 2];
  float w3 = cdw[c * 9 + 3], w4 = cdw[c * 9 + 4], w5 = cdw[c * 9 + 5];
  float w6 = cdw[c * 9 + 6], w7 = cdw[c * 9 + 7], w8 = cdw[c * 9 + 8];
  float* outp = XA + (size_t)blk * N_HW;
  for (int i = tid; i < N_HW; i += 256) {
    int y = i / 56, x = i % 56;
    const float* p0 = &sm[y * 58 + x];
    float a = p0[0] * w0 + p0[1] * w1 + p0[2] * w2
            + p0[58] * w3 + p0[59] * w4 + p0[60] * w5
            + p0[116] * w6 + p0[117] * w7 + p0[118] * w8;
    outp[i] = a;
  }
}

// ---------------- fp32 GEMM: C[M,NG] (+)= A[M,K] @ B[K,NG] ----------------
// A row-major lda=800 (pre-offset gw slice); B/C pitch NG.
// Tile 64x128, 256 threads, 4x8 micro-tile, BK=16.
__global__ __launch_bounds__(256) void gemm_f32(
    const float* __restrict__ A, const float* __restrict__ B, float* __restrict__ C,
    int K, int accum) {
  __shared__ float As[16][68];
  __shared__ float Bs[16][132];
  int n0 = blockIdx.x * 128;
  int m0 = blockIdx.y * 64;
  int tid = threadIdx.x;
  int tx = tid & 15, ty = tid >> 4;
  float acc[4][8];
#pragma unroll
  for (int i = 0; i < 4; i++)
#pragma unroll
    for (int j = 0; j < 8; j++) acc[i][j] = 0.f;

  int arow = tid >> 2, akk = (tid & 3) * 4;
  int bkk = tid >> 4, bcol = (tid & 15) * 8;

  for (int k0 = 0; k0 < K; k0 += 16) {
    float4 av = *(const float4*)(A + (size_t)(m0 + arow) * DIMC + k0 + akk);
    As[akk + 0][arow] = av.x;
    As[akk + 1][arow] = av.y;
    As[akk + 2][arow] = av.z;
    As[akk + 3][arow] = av.w;
    const float* bp = B + (size_t)(k0 + bkk) * NG + n0 + bcol;
    *(float4*)&Bs[bkk][bcol]     = *(const float4*)bp;
    *(float4*)&Bs[bkk][bcol + 4] = *(const float4*)(bp + 4);
    __syncthreads();
#pragma unroll
    for (int kk = 0; kk < 16; kk++) {
      float bv[8];
      *(float4*)&bv[0] = *(const float4*)&Bs[kk][tx * 4];
      *(float4*)&bv[4] = *(const float4*)&Bs[kk][64 + tx * 4];
#pragma unroll
      for (int i = 0; i < 4; i++) {
        float a = As[kk][ty * 4 + i];
#pragma unroll
        for (int j = 0; j < 8; j++) acc[i][j] += a * bv[j];
      }
    }
    __syncthreads();
  }

#pragma unroll
  for (int i = 0; i < 4; i++) {
    float* cp = C + (size_t)(m0 + ty * 4 + i) * NG + n0 + tx * 4;
    if (accum) {
      float4 c0 = *(float4*)cp;
      float4 c1 = *(float4*)(cp + 64);
      c0.x += acc[i][0]; c0.y += acc[i][1]; c0.z += acc[i][2]; c0.w += acc[i][3];
      c1.x += acc[i][4]; c1.y += acc[i][5]; c1.z += acc[i][6]; c1.w += acc[i][7];
      *(float4*)cp = c0;
      *(float4*)(cp + 64) = c1;
    } else {
      *(float4*)cp       = make_float4(acc[i][0], acc[i][1], acc[i][2], acc[i][3]);
      *(float4*)(cp + 64) = make_float4(acc[i][4], acc[i][5], acc[i][6], acc[i][7]);
    }
  }
}

// ------- head: layer-4 stats + norm + dwconv on 2x2 patch, per (c,bg) block -------
__global__ __launch_bounds__(256) void head_m4(
    const float* __restrict__ HT, const float* __restrict__ in_g, const float* __restrict__ in_b,
    const float* __restrict__ cdw, float* __restrict__ m4, float* __restrict__ meanH) {
  int blk = blockIdx.x;            // cl*G + bg, cl in [0,192)
  int cl = blk >> 4;
  int c = 608 + cl;
  int tid = threadIdx.x;
  const float* row = HT + (size_t)blk * N_HW;
  float s = 0.f, s2 = 0.f;
  for (int i = tid; i < N_HW; i += 256) {
    float xv = row[i];
    s += xv; s2 += xv * xv;
  }
  __shared__ float red[256], red2[256];
  red[tid] = s; red2[tid] = s2;
  __syncthreads();
  for (int o = 128; o > 0; o >>= 1) {
    if (tid < o) { red[tid] += red[tid + o]; red2[tid] += red2[tid + o]; }
    __syncthreads();
  }
  if (tid == 0) {
    float mean = red[0] * (1.f / N_HW);
    float var = fmaxf(red2[0] * (1.f / N_HW) - mean * mean, 0.f);
    float sc = in_g[c] * rsqrtf(var + EPS);
    float sh = in_b[c] - mean * sc;
    float val[4][4];
#pragma unroll
    for (int dy = 0; dy < 4; dy++)
#pragma unroll
      for (int dx = 0; dx < 4; dx++)
        val[dy][dx] = fmaxf(row[(25 + dy) * 56 + 25 + dx] * sc + sh, 0.f);
    const float* w = cdw + c * 9;
    float acc = 0.f;
#pragma unroll
    for (int oy = 1; oy < 3; oy++)
#pragma unroll
      for (int ox = 1; ox < 3; ox++)
#pragma unroll
        for (int ky = 0; ky < 3; ky++)
#pragma unroll
          for (int kx = 0; kx < 3; kx++)
            acc += val[oy + ky - 1][ox + kx - 1] * w[ky * 3 + kx];
    m4[blk] = acc * 0.25f;
    meanH[blk] = 0.25f * (row[26 * 56 + 26] + row[26 * 56 + 27] +
                          row[27 * 56 + 26] + row[27 * 56 + 27]);
  }
}

__global__ __launch_bounds__(256) void head_mix(
    const float* __restrict__ gw, const float* __restrict__ m4, const float* __restrict__ meanH,
    float* __restrict__ out_pre) {
  int idx = blockIdx.x * 256 + threadIdx.x;   // bg*192 + j
  if (idx >= G * 192) return;
  int j = idx % 192;
  int bg = idx / 192;
  float acc = meanH[j * G + bg];
  const float* grow = gw + (size_t)(608 + j) * DIMC + 608;
  for (int c = 0; c < 192; c++) acc += grow[c] * m4[c * G + bg];
  out_pre[idx] = acc;
}

__global__ __launch_bounds__(256) void head_fc(
    const float* __restrict__ out_pre, const float* __restrict__ fc_w,
    const float* __restrict__ fc_b, float* __restrict__ outg) {
  int idx = blockIdx.x * 256 + threadIdx.x;   // bg*1000 + t
  if (idx >= G * 1000) return;
  int t = idx % 1000;
  int bg = idx / 1000;
  float acc = fc_b[t];
  const float* wr = fc_w + (size_t)t * 192;
  const float* hr = out_pre + (size_t)bg * 192;
  for (int j = 0; j < 192; j++) acc += wr[j] * hr[j];
  outg[idx] = acc;
}

extern "C" void kernel_launch(void* const* d_in, const int* in_sizes, int n_in,
                              void* d_out, int out_size, void* d_ws, size_t ws_size,
                              hipStream_t stream) {
  const float* x      = (const float*)d_in[0];
  const float* ds_w1  = (const float*)d_in[1];
  const float* ds_b1  = (const float*)d_in[2];
  const float* bn1_g  = (const float*)d_in[3];
  const float* bn1_b  = (const float*)d_in[4];
  const float* bn1_m  = (const float*)d_in[5];
  const float* bn1_v  = (const float*)d_in[6];
  const float* ds_dw  = (const float*)d_in[7];
  const float* ds_dwb = (const float*)d_in[8];
  const float* ds_w2  = (const float*)d_in[9];
  const float* ds_b2  = (const float*)d_in[10];
  const float* bn2_g  = (const float*)d_in[11];
  const float* bn2_b  = (const float*)d_in[12];
  const float* bn2_m  = (const float*)d_in[13];
  const float* bn2_v  = (const float*)d_in[14];
  const float* cdw    = (const float*)d_in[15];
  const float* gw     = (const float*)d_in[16];
  const float* in_g   = (const float*)d_in[17];
  const float* in_b   = (const float*)d_in[18];
  const float* fc_w   = (const float*)d_in[19];
  const float* fc_b   = (const float*)d_in[20];
  float* out = (float*)d_out;
  char* ws = (char*)d_ws;

  if (ws_size < NEED) return;

  float* H     = (float*)ws;
  float* XA0   = (float*)(ws + XA0_OFF);
  float* m4    = (float*)(ws + M4_OFF);
  float* meanH = (float*)(ws + MH_OFF);
  float* opre  = (float*)(ws + OP_OFF);
  float* h1    = H + (size_t)32 * NG;    // rows [32,96)  (dead until L0 GEMM store)
  float* h2    = H + (size_t)96 * NG;    // rows [96,112)
  float* XAal  = H + (size_t)32 * NG;    // rows [32,224): XA alias for layers 1-3

  static const int R0[4]   = {0, 32, 224, 416};
  static const int SZ[4]   = {32, 192, 192, 192};
  static const int ROW0[4] = {32, 224, 416, 608};

  for (int g = 0; g < 32 / G; g++) {
    const float* xg = x + (size_t)g * G * 3 * 224 * 224;

    stem_conv1<<<16 * G * 12544 / 256, 256, 0, stream>>>(
        xg, ds_w1, ds_b1, bn1_g, bn1_b, bn1_m, bn1_v, h1);
    stem_dw<<<16 * G * N_HW / 256, 256, 0, stream>>>(h1, ds_dw, ds_dwb, h2);
    stem_pw<<<32 * G * N_HW / 256, 256, 0, stream>>>(
        h2, ds_w2, ds_b2, bn2_g, bn2_b, bn2_m, bn2_v, H);

    for (int i = 0; i < 4; i++) {
      int r0 = R0[i], s = SZ[i], row0 = ROW0[i];
      float* base = H + (size_t)r0 * NG;
      float* XA = (i == 0) ? XA0 : XAal;
      dw_fused<<<s * G, 256, 0, stream>>>(base, cdw, in_g, in_b, XA, r0);
      dim3 grid(NG / 128, (DIMC - row0) / 64);
      gemm_f32<<<grid, 256, 0, stream>>>(gw + (size_t)row0 * DIMC + r0, XA,
                                         H + (size_t)row0 * NG, s, i == 0 ? 0 : 1);
    }

    float* HT = H + (size_t)608 * NG;
    head_m4<<<192 * G, 256, 0, stream>>>(HT, in_g, in_b, cdw, m4, meanH);
    head_mix<<<(G * 192 + 255) / 256, 256, 0, stream>>>(gw, m4, meanH, opre);
    head_fc<<<(G * 1000 + 255) / 256, 256, 0, stream>>>(opre, fc_w, fc_b, out + (size_t)g * G * 1000);
  }
}

// Round 5
// 543.484 us; speedup vs baseline: 1.9180x; 1.9180x over previous
//
#include <hip/hip_runtime.h>
#include <stddef.h>

#define EPS 1e-5f
#define N_HW 3136              // 56*56
#define G 16                   // batches per group (2 groups of 16)
#define NG (G * N_HW)          // 50176 = group GEMM N dimension
#define DIMC 800

typedef unsigned short u16;
typedef __attribute__((ext_vector_type(8))) short short8;
typedef __attribute__((ext_vector_type(4))) float floatx4;

__device__ __forceinline__ u16 f2b(float f) {
  unsigned u = __float_as_uint(f);
  u += 0x7FFFu + ((u >> 16) & 1u);        // round-to-nearest-even
  return (u16)(u >> 16);
}

// ---------------- ws layout (bytes) ----------------
// XA_cat : bf16 [608][NG]   = 61,014,016
// H0     : f32  [32][NG]    =  6,422,528
// block  : f32  [192][NG]   = 38,535,168   (stem h1/h2 alias inside; tail reuses)
// gwb    : bf16 [800][800]  =  1,280,000
// smalls : m4/meanH (192*G each), opre (G*192)
static const size_t XA_OFF  = 0;
static const size_t H0_OFF  = 61014016ull;
static const size_t BLK_OFF = 67436544ull;
static const size_t GWB_OFF = 105971712ull;
static const size_t M4_OFF  = 107251712ull;
static const size_t MH_OFF  = M4_OFF + 192 * G * 4;
static const size_t OP_OFF  = MH_OFF + 192 * G * 4;
static const size_t NEED    = OP_OFF + (size_t)G * 192 * 4;   // ~107.3 MB

// ---------------- gw -> bf16 ----------------
__global__ __launch_bounds__(256) void gw2bf(const float* __restrict__ gw, u16* __restrict__ gwb) {
  int i = (blockIdx.x * 256 + threadIdx.x) * 4;   // 640000 elems, 625 blocks
  float4 v = *(const float4*)(gw + i);
  gwb[i + 0] = f2b(v.x); gwb[i + 1] = f2b(v.y);
  gwb[i + 2] = f2b(v.z); gwb[i + 3] = f2b(v.w);
}

// ---------------- stem ----------------
__global__ __launch_bounds__(256) void stem_conv1(
    const float* __restrict__ xg, const float* __restrict__ w, const float* __restrict__ b1,
    const float* __restrict__ g, const float* __restrict__ bb,
    const float* __restrict__ m, const float* __restrict__ v,
    float* __restrict__ h1) {
  int idx = blockIdx.x * 256 + threadIdx.x;       // ((c*G)+bg)*12544 + p
  int p = idx % 12544;
  int t = idx / 12544;
  int bg = t & (G - 1);
  int c = t >> 4;
  int oy = p / 112, ox = p % 112;
  float acc = b1[c];
  for (int ci = 0; ci < 3; ci++) {
    const float* xp = xg + ((size_t)(bg * 3 + ci)) * 224 * 224;
    const float* wp = w + (c * 3 + ci) * 9;
#pragma unroll
    for (int ky = 0; ky < 3; ky++) {
      int iy = oy * 2 - 1 + ky;
      if (iy < 0 || iy >= 224) continue;
#pragma unroll
      for (int kx = 0; kx < 3; kx++) {
        int ix = ox * 2 - 1 + kx;
        if (ix < 0 || ix >= 224) continue;
        acc += xp[iy * 224 + ix] * wp[ky * 3 + kx];
      }
    }
  }
  float y = (acc - m[c]) * (g[c] * rsqrtf(v[c] + EPS)) + bb[c];
  h1[idx] = fmaxf(y, 0.f);
}

__global__ __launch_bounds__(256) void stem_dw(
    const float* __restrict__ h1, const float* __restrict__ dw, const float* __restrict__ dwb,
    float* __restrict__ h2) {
  int idx = blockIdx.x * 256 + threadIdx.x;       // ((c*G)+bg)*3136 + q
  int q = idx % N_HW;
  int t = idx / N_HW;
  int bg = t & (G - 1);
  int c = t >> 4;
  int qy = q / 56, qx = q % 56;
  const float* plane = h1 + (size_t)(c * G + bg) * 12544;
  float acc = dwb[c];
#pragma unroll
  for (int ky = 0; ky < 3; ky++) {
    int iy = qy * 2 - 1 + ky;
    if (iy < 0 || iy >= 112) continue;
#pragma unroll
    for (int kx = 0; kx < 3; kx++) {
      int ix = qx * 2 - 1 + kx;
      if (ix < 0 || ix >= 112) continue;
      acc += plane[iy * 112 + ix] * dw[c * 9 + ky * 3 + kx];
    }
  }
  h2[idx] = acc;
}

__global__ __launch_bounds__(256) void stem_pw(
    const float* __restrict__ h2, const float* __restrict__ w2, const float* __restrict__ b2,
    const float* __restrict__ g, const float* __restrict__ bb,
    const float* __restrict__ m, const float* __restrict__ v,
    float* __restrict__ H0) {
  int idx = blockIdx.x * 256 + threadIdx.x;       // ((o*G)+bg)*3136 + q
  int q = idx % N_HW;
  int t = idx / N_HW;
  int bg = t & (G - 1);
  int o = t >> 4;
  float acc = b2[o];
#pragma unroll
  for (int c = 0; c < 16; c++) acc += w2[o * 16 + c] * h2[(size_t)(c * G + bg) * N_HW + q];
  float y = (acc - m[o]) * (g[o] * rsqrtf(v[o] + EPS)) + bb[o];
  H0[idx] = y;
}

// ------- fused instance-norm stats + norm + relu + depthwise 3x3 (pad 1) -------
// base: fp32 input block, rows cl*G+bg (pitch-per-row N_HW, channel pitch NG).
// XA: bf16 out rows of XA_cat, pre-offset to channel r0. cdw/gamma/beta at cdwoff+cl.
__global__ __launch_bounds__(256) void dw_fused(
    const float* __restrict__ base, const float* __restrict__ cdw,
    const float* __restrict__ in_g, const float* __restrict__ in_b,
    u16* __restrict__ XA, int cdwoff) {
  __shared__ float sm[58 * 58];
  __shared__ float red[256], red2[256];
  __shared__ float ssc, ssh;
  int blk = blockIdx.x;            // cl*G + bg
  int cl = blk >> 4;
  int c = cdwoff + cl;
  int tid = threadIdx.x;
  for (int i = tid; i < 58 * 58; i += 256) sm[i] = 0.f;
  __syncthreads();
  const float* row = base + (size_t)blk * N_HW;
  float s = 0.f, s2 = 0.f;
  for (int i = tid; i < N_HW; i += 256) {
    float xv = row[i];
    s += xv; s2 += xv * xv;
    int y = i / 56, x = i % 56;
    sm[(y + 1) * 58 + x + 1] = xv;
  }
  red[tid] = s; red2[tid] = s2;
  __syncthreads();
  for (int o = 128; o > 0; o >>= 1) {
    if (tid < o) { red[tid] += red[tid + o]; red2[tid] += red2[tid + o]; }
    __syncthreads();
  }
  if (tid == 0) {
    float mean = red[0] * (1.f / N_HW);
    float var = fmaxf(red2[0] * (1.f / N_HW) - mean * mean, 0.f);
    float sc = in_g[c] * rsqrtf(var + EPS);
    ssc = sc; ssh = in_b[c] - mean * sc;
  }
  __syncthreads();
  float sc = ssc, sh = ssh;
  for (int i = tid; i < N_HW; i += 256) {
    int y = i / 56, x = i % 56;
    int pos = (y + 1) * 58 + x + 1;
    sm[pos] = fmaxf(sm[pos] * sc + sh, 0.f);
  }
  __syncthreads();
  float w0 = cdw[c * 9 + 0], w1 = cdw[c * 9 + 1], w2 = cdw[c * 9 + 2];
  float w3 = cdw[c * 9 + 3], w4 = cdw[c * 9 + 4], w5 = cdw[c * 9 + 5];
  float w6 = cdw[c * 9 + 6], w7 = cdw[c * 9 + 7], w8 = cdw[c * 9 + 8];
  u16* outp = XA + (size_t)blk * N_HW;
  for (int i = tid; i < N_HW; i += 256) {
    int y = i / 56, x = i % 56;
    const float* p0 = &sm[y * 58 + x];
    float a = p0[0] * w0 + p0[1] * w1 + p0[2] * w2
            + p0[58] * w3 + p0[59] * w4 + p0[60] * w5
            + p0[116] * w6 + p0[117] * w7 + p0[118] * w8;
    outp[i] = f2b(a);
  }
}

// ---------------- MFMA GEMM: C[192][NG] = A[192][K] @ B[K][NG] (pure store) ----
// A: gwb slice (bf16, lda=DIMC). B: XA_cat (bf16, pitch NG). C: fp32, pitch NG.
// Tile 64x128, 4 waves (2x2), wave tile 32x64 = 2x4 frags of 16x16, BK=32.
// B-frag gathered from LDS with XOR-16 column swizzle (conflict-free groups).
__global__ __launch_bounds__(256) void gemm_mfma(
    const u16* __restrict__ A, const u16* __restrict__ B, float* __restrict__ C, int K) {
  __shared__ u16 As[64][40];    // pitch 80 B
  __shared__ u16 Bs[32][128];   // pitch 256 B, XOR-swizzled columns
  int n0 = blockIdx.x * 128;
  int m0 = blockIdx.y * 64;
  int tid = threadIdx.x;
  int wave = tid >> 6, lane = tid & 63;
  int wm = wave >> 1, wn = wave & 1;
  int lg = lane >> 4, li = lane & 15;
  floatx4 acc[2][4] = {};

  int a_row = tid >> 2, a_k = (tid & 3) * 8;     // 64 rows x 32k
  int b_k = tid >> 3, b_n = (tid & 7) * 16;      // 32 rows x 128n
  int b_nx = b_n ^ ((b_k >> 3) << 4);            // XOR-16 swizzle by k-group
  const u16* Ag = A + (size_t)(m0 + a_row) * DIMC + a_k;
  const u16* Bg = B + (size_t)b_k * NG + n0 + b_n;

  for (int k0 = 0; k0 < K; k0 += 32) {
    *(uint4*)&As[a_row][a_k] = *(const uint4*)(Ag + k0);
    const u16* bp = Bg + (size_t)k0 * NG;
    *(uint4*)&Bs[b_k][b_nx]     = *(const uint4*)bp;
    *(uint4*)&Bs[b_k][b_nx + 8] = *(const uint4*)(bp + 8);
    __syncthreads();
    short8 aF0 = *(const short8*)&As[wm * 32 + li][lg * 8];
    short8 aF1 = *(const short8*)&As[wm * 32 + 16 + li][lg * 8];
#pragma unroll
    for (int ni = 0; ni < 4; ni++) {
      int colx = ((wn * 64 + ni * 16) ^ (lg << 4)) + li;
      short8 bF;
#pragma unroll
      for (int e = 0; e < 8; e++) bF[e] = (short)Bs[lg * 8 + e][colx];
      acc[0][ni] = __builtin_amdgcn_mfma_f32_16x16x32_bf16(aF0, bF, acc[0][ni], 0, 0, 0);
      acc[1][ni] = __builtin_amdgcn_mfma_f32_16x16x32_bf16(aF1, bF, acc[1][ni], 0, 0, 0);
    }
    __syncthreads();
  }
#pragma unroll
  for (int mi = 0; mi < 2; mi++) {
#pragma unroll
    for (int ni = 0; ni < 4; ni++) {
      int row = m0 + wm * 32 + mi * 16 + lg * 4;   // C/D: col=lane&15, row=lg*4+r
      int col = n0 + wn * 64 + ni * 16 + li;
      float* cp = C + (size_t)row * NG + col;
#pragma unroll
      for (int r = 0; r < 4; r++) cp[(size_t)r * NG] = acc[mi][ni][r];
    }
  }
}

// ------- head: layer-4 stats + norm + dwconv on 2x2 patch, per (c,bg) block -------
__global__ __launch_bounds__(256) void head_m4(
    const float* __restrict__ HT, const float* __restrict__ in_g, const float* __restrict__ in_b,
    const float* __restrict__ cdw, float* __restrict__ m4, float* __restrict__ meanH) {
  int blk = blockIdx.x;            // cl*G + bg, cl in [0,192)
  int cl = blk >> 4;
  int c = 608 + cl;
  int tid = threadIdx.x;
  const float* row = HT + (size_t)blk * N_HW;
  float s = 0.f, s2 = 0.f;
  for (int i = tid; i < N_HW; i += 256) {
    float xv = row[i];
    s += xv; s2 += xv * xv;
  }
  __shared__ float red[256], red2[256];
  red[tid] = s; red2[tid] = s2;
  __syncthreads();
  for (int o = 128; o > 0; o >>= 1) {
    if (tid < o) { red[tid] += red[tid + o]; red2[tid] += red2[tid + o]; }
    __syncthreads();
  }
  if (tid == 0) {
    float mean = red[0] * (1.f / N_HW);
    float var = fmaxf(red2[0] * (1.f / N_HW) - mean * mean, 0.f);
    float sc = in_g[c] * rsqrtf(var + EPS);
    float sh = in_b[c] - mean * sc;
    float val[4][4];
#pragma unroll
    for (int dy = 0; dy < 4; dy++)
#pragma unroll
      for (int dx = 0; dx < 4; dx++)
        val[dy][dx] = fmaxf(row[(25 + dy) * 56 + 25 + dx] * sc + sh, 0.f);
    const float* w = cdw + c * 9;
    float acc = 0.f;
#pragma unroll
    for (int oy = 1; oy < 3; oy++)
#pragma unroll
      for (int ox = 1; ox < 3; ox++)
#pragma unroll
        for (int ky = 0; ky < 3; ky++)
#pragma unroll
          for (int kx = 0; kx < 3; kx++)
            acc += val[oy + ky - 1][ox + kx - 1] * w[ky * 3 + kx];
    m4[blk] = acc * 0.25f;
    meanH[blk] = 0.25f * (row[26 * 56 + 26] + row[26 * 56 + 27] +
                          row[27 * 56 + 26] + row[27 * 56 + 27]);
  }
}

__global__ __launch_bounds__(256) void head_mix(
    const float* __restrict__ gw, const float* __restrict__ m4, const float* __restrict__ meanH,
    float* __restrict__ out_pre) {
  int idx = blockIdx.x * 256 + threadIdx.x;   // bg*192 + j
  if (idx >= G * 192) return;
  int j = idx % 192;
  int bg = idx / 192;
  float acc = meanH[j * G + bg];
  const float* grow = gw + (size_t)(608 + j) * DIMC + 608;
  for (int c = 0; c < 192; c++) acc += grow[c] * m4[c * G + bg];
  out_pre[idx] = acc;
}

__global__ __launch_bounds__(256) void head_fc(
    const float* __restrict__ out_pre, const float* __restrict__ fc_w,
    const float* __restrict__ fc_b, float* __restrict__ outg) {
  int idx = blockIdx.x * 256 + threadIdx.x;   // bg*1000 + t
  if (idx >= G * 1000) return;
  int t = idx % 1000;
  int bg = idx / 1000;
  float acc = fc_b[t];
  const float* wr = fc_w + (size_t)t * 192;
  const float* hr = out_pre + (size_t)bg * 192;
  for (int j = 0; j < 192; j++) acc += wr[j] * hr[j];
  outg[idx] = acc;
}

extern "C" void kernel_launch(void* const* d_in, const int* in_sizes, int n_in,
                              void* d_out, int out_size, void* d_ws, size_t ws_size,
                              hipStream_t stream) {
  const float* x      = (const float*)d_in[0];
  const float* ds_w1  = (const float*)d_in[1];
  const float* ds_b1  = (const float*)d_in[2];
  const float* bn1_g  = (const float*)d_in[3];
  const float* bn1_b  = (const float*)d_in[4];
  const float* bn1_m  = (const float*)d_in[5];
  const float* bn1_v  = (const float*)d_in[6];
  const float* ds_dw  = (const float*)d_in[7];
  const float* ds_dwb = (const float*)d_in[8];
  const float* ds_w2  = (const float*)d_in[9];
  const float* ds_b2  = (const float*)d_in[10];
  const float* bn2_g  = (const float*)d_in[11];
  const float* bn2_b  = (const float*)d_in[12];
  const float* bn2_m  = (const float*)d_in[13];
  const float* bn2_v  = (const float*)d_in[14];
  const float* cdw    = (const float*)d_in[15];
  const float* gw     = (const float*)d_in[16];
  const float* in_g   = (const float*)d_in[17];
  const float* in_b   = (const float*)d_in[18];
  const float* fc_w   = (const float*)d_in[19];
  const float* fc_b   = (const float*)d_in[20];
  float* out = (float*)d_out;
  char* ws = (char*)d_ws;

  if (ws_size < NEED) return;

  u16*   XAc   = (u16*)(ws + XA_OFF);
  float* H0    = (float*)(ws + H0_OFF);
  float* block = (float*)(ws + BLK_OFF);
  u16*   gwb   = (u16*)(ws + GWB_OFF);
  float* m4    = (float*)(ws + M4_OFF);
  float* meanH = (float*)(ws + MH_OFF);
  float* opre  = (float*)(ws + OP_OFF);
  float* h1    = block;                             // 12.85 MB, dead after stem
  float* h2    = block + (size_t)16 * G * 12544;    // 3.2 MB

  gw2bf<<<625, 256, 0, stream>>>(gw, gwb);

  // per-layer: dw_fused reads `in`, appends XA_cat[r0:r0+s); gemm computes next
  // block = gwb[rA:rA+192, 0:K] @ XA_cat[0:K]  (pure store, fp32 out)
  static const int CDWOFF[4] = {0, 32, 224, 416};   // = r0 of the dw layer
  static const int SZ[4]     = {32, 192, 192, 192};
  static const int RA[4]     = {32, 224, 416, 608}; // gemm output channel base
  static const int KK[4]     = {32, 224, 416, 608};

  for (int g = 0; g < 32 / G; g++) {
    const float* xg = x + (size_t)g * G * 3 * 224 * 224;

    stem_conv1<<<16 * G * 12544 / 256, 256, 0, stream>>>(
        xg, ds_w1, ds_b1, bn1_g, bn1_b, bn1_m, bn1_v, h1);
    stem_dw<<<16 * G * N_HW / 256, 256, 0, stream>>>(h1, ds_dw, ds_dwb, h2);
    stem_pw<<<32 * G * N_HW / 256, 256, 0, stream>>>(
        h2, ds_w2, ds_b2, bn2_g, bn2_b, bn2_m, bn2_v, H0);

    for (int i = 0; i < 4; i++) {
      const float* in = (i == 0) ? H0 : block;
      dw_fused<<<SZ[i] * G, 256, 0, stream>>>(
          in, cdw, in_g, in_b, XAc + (size_t)CDWOFF[i] * NG, CDWOFF[i]);
      dim3 grid(NG / 128, 3);
      gemm_mfma<<<grid, 256, 0, stream>>>(gwb + (size_t)RA[i] * DIMC, XAc, block, KK[i]);
    }

    head_m4<<<192 * G, 256, 0, stream>>>(block, in_g, in_b, cdw, m4, meanH);
    head_mix<<<(G * 192 + 255) / 256, 256, 0, stream>>>(gw, m4, meanH, opre);
    head_fc<<<(G * 1000 + 255) / 256, 256, 0, stream>>>(opre, fc_w, fc_b, out + (size_t)g * G * 1000);
  }
}

// Round 7
// 467.263 us; speedup vs baseline: 2.2309x; 1.1631x over previous
//
#include <hip/hip_runtime.h>
#include <stddef.h>

#define EPS 1e-5f
#define N_HW 3136              // 56*56
#define G 16                   // batches per group (2 groups of 16)
#define NG (G * N_HW)          // 50176 = group GEMM N dimension
#define DIMC 800

typedef unsigned short u16;
typedef __attribute__((ext_vector_type(8))) short short8;
typedef __attribute__((ext_vector_type(4))) float floatx4;

__device__ __forceinline__ u16 f2b(float f) {
  unsigned u = __float_as_uint(f);
  u += 0x7FFFu + ((u >> 16) & 1u);        // round-to-nearest-even
  return (u16)(u >> 16);
}

// ---------------- ws layout (bytes) ----------------
// XA_cat : bf16 [608][NG]   = 61,014,016
// H0     : f32  [32][NG]    =  6,422,528
// block  : f32  [192][NG]   = 38,535,168   (stem h1/h2 alias inside)
// gwb    : bf16 [800][800]  =  1,280,000
// smalls : m4/meanH (192*G each), opre (G*192)
static const size_t XA_OFF  = 0;
static const size_t H0_OFF  = 61014016ull;
static const size_t BLK_OFF = 67436544ull;
static const size_t GWB_OFF = 105971712ull;
static const size_t M4_OFF  = 107251712ull;
static const size_t MH_OFF  = M4_OFF + 192 * G * 4;
static const size_t OP_OFF  = MH_OFF + 192 * G * 4;
static const size_t NEED    = OP_OFF + (size_t)G * 192 * 4;   // ~107.3 MB

// ---------------- gw -> bf16 ----------------
__global__ __launch_bounds__(256) void gw2bf(const float* __restrict__ gw, u16* __restrict__ gwb) {
  int i = (blockIdx.x * 256 + threadIdx.x) * 4;   // 640000 elems, 625 blocks
  float4 v = *(const float4*)(gw + i);
  gwb[i + 0] = f2b(v.x); gwb[i + 1] = f2b(v.y);
  gwb[i + 2] = f2b(v.z); gwb[i + 3] = f2b(v.w);
}

// ---------------- stem conv1: LDS-tiled, all 16 ch per block ----------------
// block = (bg, 8-row output strip). Input tile 3ch x 17 rows x 226 cols in LDS.
#define XT_PITCH 226
#define XT_CH (17 * XT_PITCH)          // 3842
__global__ __launch_bounds__(256) void stem_conv1(
    const float* __restrict__ xg, const float* __restrict__ w, const float* __restrict__ b1,
    const float* __restrict__ g, const float* __restrict__ bb,
    const float* __restrict__ m, const float* __restrict__ v,
    float* __restrict__ h1) {
  __shared__ float xt[3 * XT_CH];      // 46.1 KB
  __shared__ float wt[16 * 27];
  __shared__ float mulc[16], addc[16];
  int blk = blockIdx.x;                // s + 14*bg
  int s = blk % 14;
  int bg = blk / 14;
  int tid = threadIdx.x;

  for (int e = tid; e < 432; e += 256) wt[e] = w[e];   // FIX: 432 > 256 threads
  if (tid < 16) {
    float A = g[tid] * rsqrtf(v[tid] + EPS);
    mulc[tid] = A;
    addc[tid] = (b1[tid] - m[tid]) * A + bb[tid];
  }
  int iy0 = 16 * s - 1;
  for (int e = tid; e < 3 * XT_CH; e += 256) {
    int ci = e / XT_CH;
    int rem = e - ci * XT_CH;
    int r = rem / XT_PITCH;
    int cc = rem - r * XT_PITCH;
    int iy = iy0 + r, ix = cc - 1;
    float val = 0.f;
    if (iy >= 0 && iy < 224 && ix >= 0 && ix < 224)
      val = xg[((size_t)(bg * 3 + ci)) * 224 * 224 + iy * 224 + ix];
    xt[e] = val;
  }
  __syncthreads();

  for (int p = tid; p < 8 * 112; p += 256) {
    int oyl = p / 112, ox = p - oyl * 112;
    float xv[27];
#pragma unroll
    for (int ci = 0; ci < 3; ci++)
#pragma unroll
      for (int ky = 0; ky < 3; ky++)
#pragma unroll
        for (int kx = 0; kx < 3; kx++)
          xv[ci * 9 + ky * 3 + kx] = xt[ci * XT_CH + (2 * oyl + ky) * XT_PITCH + 2 * ox + kx];
    int oy = 8 * s + oyl;
#pragma unroll
    for (int c = 0; c < 16; c++) {
      float acc = 0.f;
#pragma unroll
      for (int t = 0; t < 27; t++) acc += xv[t] * wt[c * 27 + t];
      float y = acc * mulc[c] + addc[c];
      h1[(size_t)(c * G + bg) * 12544 + oy * 112 + ox] = fmaxf(y, 0.f);
    }
  }
}

__global__ __launch_bounds__(256) void stem_dw(
    const float* __restrict__ h1, const float* __restrict__ dw, const float* __restrict__ dwb,
    float* __restrict__ h2) {
  int idx = blockIdx.x * 256 + threadIdx.x;       // ((c*G)+bg)*3136 + q
  int q = idx % N_HW;
  int t = idx / N_HW;
  int bg = t & (G - 1);
  int c = t >> 4;
  int qy = q / 56, qx = q % 56;
  const float* plane = h1 + (size_t)(c * G + bg) * 12544;
  float acc = dwb[c];
#pragma unroll
  for (int ky = 0; ky < 3; ky++) {
    int iy = qy * 2 - 1 + ky;
    if (iy < 0 || iy >= 112) continue;
#pragma unroll
    for (int kx = 0; kx < 3; kx++) {
      int ix = qx * 2 - 1 + kx;
      if (ix < 0 || ix >= 112) continue;
      acc += plane[iy * 112 + ix] * dw[c * 9 + ky * 3 + kx];
    }
  }
  h2[idx] = acc;
}

__global__ __launch_bounds__(256) void stem_pw(
    const float* __restrict__ h2, const float* __restrict__ w2, const float* __restrict__ b2,
    const float* __restrict__ g, const float* __restrict__ bb,
    const float* __restrict__ m, const float* __restrict__ v,
    float* __restrict__ H0) {
  int idx = blockIdx.x * 256 + threadIdx.x;       // ((o*G)+bg)*3136 + q
  int q = idx % N_HW;
  int t = idx / N_HW;
  int bg = t & (G - 1);
  int o = t >> 4;
  float acc = b2[o];
#pragma unroll
  for (int c = 0; c < 16; c++) acc += w2[o * 16 + c] * h2[(size_t)(c * G + bg) * N_HW + q];
  float y = (acc - m[o]) * (g[o] * rsqrtf(v[o] + EPS)) + bb[o];
  H0[idx] = y;
}

// ------- fused instance-norm stats + norm + relu + depthwise 3x3 (pad 1) -------
__global__ __launch_bounds__(256) void dw_fused(
    const float* __restrict__ base, const float* __restrict__ cdw,
    const float* __restrict__ in_g, const float* __restrict__ in_b,
    u16* __restrict__ XA, int cdwoff) {
  __shared__ float sm[58 * 58];
  __shared__ float red[256], red2[256];
  __shared__ float ssc, ssh;
  int blk = blockIdx.x;            // cl*G + bg
  int cl = blk >> 4;
  int c = cdwoff + cl;
  int tid = threadIdx.x;
  for (int i = tid; i < 58 * 58; i += 256) sm[i] = 0.f;
  __syncthreads();
  const float* row = base + (size_t)blk * N_HW;
  float s = 0.f, s2 = 0.f;
  for (int i = tid; i < N_HW; i += 256) {
    float xv = row[i];
    s += xv; s2 += xv * xv;
    int y = i / 56, x = i % 56;
    sm[(y + 1) * 58 + x + 1] = xv;
  }
  red[tid] = s; red2[tid] = s2;
  __syncthreads();
  for (int o = 128; o > 0; o >>= 1) {
    if (tid < o) { red[tid] += red[tid + o]; red2[tid] += red2[tid + o]; }
    __syncthreads();
  }
  if (tid == 0) {
    float mean = red[0] * (1.f / N_HW);
    float var = fmaxf(red2[0] * (1.f / N_HW) - mean * mean, 0.f);
    float sc = in_g[c] * rsqrtf(var + EPS);
    ssc = sc; ssh = in_b[c] - mean * sc;
  }
  __syncthreads();
  float sc = ssc, sh = ssh;
  for (int i = tid; i < N_HW; i += 256) {
    int y = i / 56, x = i % 56;
    int pos = (y + 1) * 58 + x + 1;
    sm[pos] = fmaxf(sm[pos] * sc + sh, 0.f);
  }
  __syncthreads();
  float w0 = cdw[c * 9 + 0], w1 = cdw[c * 9 + 1], w2 = cdw[c * 9 + 2];
  float w3 = cdw[c * 9 + 3], w4 = cdw[c * 9 + 4], w5 = cdw[c * 9 + 5];
  float w6 = cdw[c * 9 + 6], w7 = cdw[c * 9 + 7], w8 = cdw[c * 9 + 8];
  u16* outp = XA + (size_t)blk * N_HW;
  for (int i = tid; i < N_HW; i += 256) {
    int y = i / 56, x = i % 56;
    const float* p0 = &sm[y * 58 + x];
    float a = p0[0] * w0 + p0[1] * w1 + p0[2] * w2
            + p0[58] * w3 + p0[59] * w4 + p0[60] * w5
            + p0[116] * w6 + p0[117] * w7 + p0[118] * w8;
    outp[i] = f2b(a);
  }
}

// ---------------- MFMA GEMM: C[192][NG] = A[192][K] @ B[K][NG] (pure store) ----
// Full-M tile: grid (NG/128). 4 waves as 2x2, wave tile 96x64 = 6x4 frags, BK=32.
// B panel read exactly once per block.
__global__ __launch_bounds__(256) void gemm_mfma(
    const u16* __restrict__ A, const u16* __restrict__ B, float* __restrict__ C, int K) {
  __shared__ u16 As[192][40];   // pitch 80 B
  __shared__ u16 Bs[32][128];   // pitch 256 B, XOR-16 swizzled columns
  int n0 = blockIdx.x * 128;
  int tid = threadIdx.x;
  int wave = tid >> 6, lane = tid & 63;
  int wm = wave >> 1, wn = wave & 1;           // 2x2 waves -> (96m, 64n) tiles
  int lg = lane >> 4, li = lane & 15;
  floatx4 acc[6][4] = {};

  int a_row = tid >> 2, a_k = (tid & 3) * 8;   // 64 rows/pass x 3 passes
  int b_k = tid >> 3, b_n = (tid & 7) * 16;
  int b_nx = b_n ^ ((b_k >> 3) << 4);
  const u16* Ag = A + (size_t)a_row * DIMC + a_k;
  const u16* Bg = B + (size_t)b_k * NG + n0 + b_n;

  for (int k0 = 0; k0 < K; k0 += 32) {
    *(uint4*)&As[a_row][a_k]       = *(const uint4*)(Ag + k0);
    *(uint4*)&As[a_row + 64][a_k]  = *(const uint4*)(Ag + (size_t)64 * DIMC + k0);
    *(uint4*)&As[a_row + 128][a_k] = *(const uint4*)(Ag + (size_t)128 * DIMC + k0);
    const u16* bp = Bg + (size_t)k0 * NG;
    *(uint4*)&Bs[b_k][b_nx]     = *(const uint4*)bp;
    *(uint4*)&Bs[b_k][b_nx + 8] = *(const uint4*)(bp + 8);
    __syncthreads();
    short8 aF[6];
#pragma unroll
    for (int mi = 0; mi < 6; mi++)
      aF[mi] = *(const short8*)&As[wm * 96 + mi * 16 + li][lg * 8];
#pragma unroll
    for (int ni = 0; ni < 4; ni++) {
      int colx = ((wn * 64 + ni * 16) ^ (lg << 4)) + li;
      short8 bF;
#pragma unroll
      for (int e = 0; e < 8; e++) bF[e] = (short)Bs[lg * 8 + e][colx];
#pragma unroll
      for (int mi = 0; mi < 6; mi++)
        acc[mi][ni] = __builtin_amdgcn_mfma_f32_16x16x32_bf16(aF[mi], bF, acc[mi][ni], 0, 0, 0);
    }
    __syncthreads();
  }
#pragma unroll
  for (int mi = 0; mi < 6; mi++) {
#pragma unroll
    for (int ni = 0; ni < 4; ni++) {
      int row = wm * 96 + mi * 16 + lg * 4;    // C/D: col=lane&15, row=lg*4+r
      int col = n0 + wn * 64 + ni * 16 + li;
      float* cp = C + (size_t)row * NG + col;
#pragma unroll
      for (int r = 0; r < 4; r++) cp[(size_t)r * NG] = acc[mi][ni][r];
    }
  }
}

// ------- head: layer-4 stats + norm + dwconv on 2x2 patch, per (c,bg) block -------
__global__ __launch_bounds__(256) void head_m4(
    const float* __restrict__ HT, const float* __restrict__ in_g, const float* __restrict__ in_b,
    const float* __restrict__ cdw, float* __restrict__ m4, float* __restrict__ meanH) {
  int blk = blockIdx.x;            // cl*G + bg, cl in [0,192)
  int cl = blk >> 4;
  int c = 608 + cl;
  int tid = threadIdx.x;
  const float* row = HT + (size_t)blk * N_HW;
  float s = 0.f, s2 = 0.f;
  for (int i = tid; i < N_HW; i += 256) {
    float xv = row[i];
    s += xv; s2 += xv * xv;
  }
  __shared__ float red[256], red2[256];
  red[tid] = s; red2[tid] = s2;
  __syncthreads();
  for (int o = 128; o > 0; o >>= 1) {
    if (tid < o) { red[tid] += red[tid + o]; red2[tid] += red2[tid + o]; }
    __syncthreads();
  }
  if (tid == 0) {
    float mean = red[0] * (1.f / N_HW);
    float var = fmaxf(red2[0] * (1.f / N_HW) - mean * mean, 0.f);
    float sc = in_g[c] * rsqrtf(var + EPS);
    float sh = in_b[c] - mean * sc;
    float val[4][4];
#pragma unroll
    for (int dy = 0; dy < 4; dy++)
#pragma unroll
      for (int dx = 0; dx < 4; dx++)
        val[dy][dx] = fmaxf(row[(25 + dy) * 56 + 25 + dx] * sc + sh, 0.f);
    const float* w = cdw + c * 9;
    float acc = 0.f;
#pragma unroll
    for (int oy = 1; oy < 3; oy++)
#pragma unroll
      for (int ox = 1; ox < 3; ox++)
#pragma unroll
        for (int ky = 0; ky < 3; ky++)
#pragma unroll
          for (int kx = 0; kx < 3; kx++)
            acc += val[oy + ky - 1][ox + kx - 1] * w[ky * 3 + kx];
    m4[blk] = acc * 0.25f;
    meanH[blk] = 0.25f * (row[26 * 56 + 26] + row[26 * 56 + 27] +
                          row[27 * 56 + 26] + row[27 * 56 + 27]);
  }
}

__global__ __launch_bounds__(256) void head_mix(
    const float* __restrict__ gw, const float* __restrict__ m4, const float* __restrict__ meanH,
    float* __restrict__ out_pre) {
  int idx = blockIdx.x * 256 + threadIdx.x;   // bg*192 + j
  if (idx >= G * 192) return;
  int j = idx % 192;
  int bg = idx / 192;
  float acc = meanH[j * G + bg];
  const float* grow = gw + (size_t)(608 + j) * DIMC + 608;
  for (int c = 0; c < 192; c++) acc += grow[c] * m4[c * G + bg];
  out_pre[idx] = acc;
}

__global__ __launch_bounds__(256) void head_fc(
    const float* __restrict__ out_pre, const float* __restrict__ fc_w,
    const float* __restrict__ fc_b, float* __restrict__ outg) {
  int idx = blockIdx.x * 256 + threadIdx.x;   // bg*1000 + t
  if (idx >= G * 1000) return;
  int t = idx % 1000;
  int bg = idx / 1000;
  float acc = fc_b[t];
  const float* wr = fc_w + (size_t)t * 192;
  const float* hr = out_pre + (size_t)bg * 192;
  for (int j = 0; j < 192; j++) acc += wr[j] * hr[j];
  outg[idx] = acc;
}

extern "C" void kernel_launch(void* const* d_in, const int* in_sizes, int n_in,
                              void* d_out, int out_size, void* d_ws, size_t ws_size,
                              hipStream_t stream) {
  const float* x      = (const float*)d_in[0];
  const float* ds_w1  = (const float*)d_in[1];
  const float* ds_b1  = (const float*)d_in[2];
  const float* bn1_g  = (const float*)d_in[3];
  const float* bn1_b  = (const float*)d_in[4];
  const float* bn1_m  = (const float*)d_in[5];
  const float* bn1_v  = (const float*)d_in[6];
  const float* ds_dw  = (const float*)d_in[7];
  const float* ds_dwb = (const float*)d_in[8];
  const float* ds_w2  = (const float*)d_in[9];
  const float* ds_b2  = (const float*)d_in[10];
  const float* bn2_g  = (const float*)d_in[11];
  const float* bn2_b  = (const float*)d_in[12];
  const float* bn2_m  = (const float*)d_in[13];
  const float* bn2_v  = (const float*)d_in[14];
  const float* cdw    = (const float*)d_in[15];
  const float* gw     = (const float*)d_in[16];
  const float* in_g   = (const float*)d_in[17];
  const float* in_b   = (const float*)d_in[18];
  const float* fc_w   = (const float*)d_in[19];
  const float* fc_b   = (const float*)d_in[20];
  float* out = (float*)d_out;
  char* ws = (char*)d_ws;

  if (ws_size < NEED) return;

  u16*   XAc   = (u16*)(ws + XA_OFF);
  float* H0    = (float*)(ws + H0_OFF);
  float* block = (float*)(ws + BLK_OFF);
  u16*   gwb   = (u16*)(ws + GWB_OFF);
  float* m4    = (float*)(ws + M4_OFF);
  float* meanH = (float*)(ws + MH_OFF);
  float* opre  = (float*)(ws + OP_OFF);
  float* h1    = block;                             // 12.85 MB, dead after stem
  float* h2    = block + (size_t)16 * G * 12544;    // 3.2 MB

  gw2bf<<<625, 256, 0, stream>>>(gw, gwb);

  static const int CDWOFF[4] = {0, 32, 224, 416};   // dw layer channel base
  static const int SZ[4]     = {32, 192, 192, 192};
  static const int RA[4]     = {32, 224, 416, 608}; // gemm output channel base
  static const int KK[4]     = {32, 224, 416, 608};

  for (int g = 0; g < 32 / G; g++) {
    const float* xg = x + (size_t)g * G * 3 * 224 * 224;

    stem_conv1<<<14 * G, 256, 0, stream>>>(
        xg, ds_w1, ds_b1, bn1_g, bn1_b, bn1_m, bn1_v, h1);
    stem_dw<<<16 * G * N_HW / 256, 256, 0, stream>>>(h1, ds_dw, ds_dwb, h2);
    stem_pw<<<32 * G * N_HW / 256, 256, 0, stream>>>(
        h2, ds_w2, ds_b2, bn2_g, bn2_b, bn2_m, bn2_v, H0);

    for (int i = 0; i < 4; i++) {
      const float* in = (i == 0) ? H0 : block;
      dw_fused<<<SZ[i] * G, 256, 0, stream>>>(
          in, cdw, in_g, in_b, XAc + (size_t)CDWOFF[i] * NG, CDWOFF[i]);
      gemm_mfma<<<NG / 128, 256, 0, stream>>>(gwb + (size_t)RA[i] * DIMC, XAc, block, KK[i]);
    }

    head_m4<<<192 * G, 256, 0, stream>>>(block, in_g, in_b, cdw, m4, meanH);
    head_mix<<<(G * 192 + 255) / 256, 256, 0, stream>>>(gw, m4, meanH, opre);
    head_fc<<<(G * 1000 + 255) / 256, 256, 0, stream>>>(opre, fc_w, fc_b, out + (size_t)g * G * 1000);
  }
}

// Round 8
// 465.357 us; speedup vs baseline: 2.2400x; 1.0041x over previous
//
#include <hip/hip_runtime.h>
#include <stddef.h>

#define EPS 1e-5f
#define N_HW 3136              // 56*56
#define G 16                   // batches per group (2 groups of 16)
#define NG (G * N_HW)          // 50176 = group GEMM N dimension
#define DIMC 800

typedef unsigned short u16;
typedef __attribute__((ext_vector_type(8))) short short8;
typedef __attribute__((ext_vector_type(4))) float floatx4;

__device__ __forceinline__ u16 f2b(float f) {
  unsigned u = __float_as_uint(f);
  u += 0x7FFFu + ((u >> 16) & 1u);        // round-to-nearest-even
  return (u16)(u >> 16);
}

// ---------------- ws layout (bytes) ----------------
// XA_cat : bf16 [608][NG]   = 61,014,016
// H0     : f32  [32][NG]    =  6,422,528
// block  : f32  [192][NG]   = 38,535,168   (stem h1/h2 alias inside)
// gwb    : bf16 [800][800]  =  1,280,000
// smalls : m4/meanH (192*G each), opre (G*192)
static const size_t XA_OFF  = 0;
static const size_t H0_OFF  = 61014016ull;
static const size_t BLK_OFF = 67436544ull;
static const size_t GWB_OFF = 105971712ull;
static const size_t M4_OFF  = 107251712ull;
static const size_t MH_OFF  = M4_OFF + 192 * G * 4;
static const size_t OP_OFF  = MH_OFF + 192 * G * 4;
static const size_t NEED    = OP_OFF + (size_t)G * 192 * 4;   // ~107.3 MB

// ---------------- gw -> bf16 ----------------
__global__ __launch_bounds__(256) void gw2bf(const float* __restrict__ gw, u16* __restrict__ gwb) {
  int i = (blockIdx.x * 256 + threadIdx.x) * 4;   // 640000 elems, 625 blocks
  float4 v = *(const float4*)(gw + i);
  gwb[i + 0] = f2b(v.x); gwb[i + 1] = f2b(v.y);
  gwb[i + 2] = f2b(v.z); gwb[i + 3] = f2b(v.w);
}

// ---------------- stem conv1: LDS-tiled, all 16 ch per block ----------------
// block = (bg, 8-row output strip). Input tile 3ch x 17 rows x 226 cols in LDS.
#define XT_PITCH 226
#define XT_CH (17 * XT_PITCH)          // 3842
__global__ __launch_bounds__(256) void stem_conv1(
    const float* __restrict__ xg, const float* __restrict__ w, const float* __restrict__ b1,
    const float* __restrict__ g, const float* __restrict__ bb,
    const float* __restrict__ m, const float* __restrict__ v,
    float* __restrict__ h1) {
  __shared__ float xt[3 * XT_CH];      // 46.1 KB
  __shared__ float wt[16 * 27];
  __shared__ float mulc[16], addc[16];
  int blk = blockIdx.x;                // s + 14*bg
  int s = blk % 14;
  int bg = blk / 14;
  int tid = threadIdx.x;

  for (int e = tid; e < 432; e += 256) wt[e] = w[e];
  if (tid < 16) {
    float A = g[tid] * rsqrtf(v[tid] + EPS);
    mulc[tid] = A;
    addc[tid] = (b1[tid] - m[tid]) * A + bb[tid];
  }
  int iy0 = 16 * s - 1;
  for (int e = tid; e < 3 * XT_CH; e += 256) {
    int ci = e / XT_CH;
    int rem = e - ci * XT_CH;
    int r = rem / XT_PITCH;
    int cc = rem - r * XT_PITCH;
    int iy = iy0 + r, ix = cc - 1;
    float val = 0.f;
    if (iy >= 0 && iy < 224 && ix >= 0 && ix < 224)
      val = xg[((size_t)(bg * 3 + ci)) * 224 * 224 + iy * 224 + ix];
    xt[e] = val;
  }
  __syncthreads();

  for (int p = tid; p < 8 * 112; p += 256) {
    int oyl = p / 112, ox = p - oyl * 112;
    float xv[27];
#pragma unroll
    for (int ci = 0; ci < 3; ci++)
#pragma unroll
      for (int ky = 0; ky < 3; ky++)
#pragma unroll
        for (int kx = 0; kx < 3; kx++)
          xv[ci * 9 + ky * 3 + kx] = xt[ci * XT_CH + (2 * oyl + ky) * XT_PITCH + 2 * ox + kx];
    int oy = 8 * s + oyl;
#pragma unroll
    for (int c = 0; c < 16; c++) {
      float acc = 0.f;
#pragma unroll
      for (int t = 0; t < 27; t++) acc += xv[t] * wt[c * 27 + t];
      float y = acc * mulc[c] + addc[c];
      h1[(size_t)(c * G + bg) * 12544 + oy * 112 + ox] = fmaxf(y, 0.f);
    }
  }
}

__global__ __launch_bounds__(256) void stem_dw(
    const float* __restrict__ h1, const float* __restrict__ dw, const float* __restrict__ dwb,
    float* __restrict__ h2) {
  int idx = blockIdx.x * 256 + threadIdx.x;       // ((c*G)+bg)*3136 + q
  int q = idx % N_HW;
  int t = idx / N_HW;
  int bg = t & (G - 1);
  int c = t >> 4;
  int qy = q / 56, qx = q % 56;
  const float* plane = h1 + (size_t)(c * G + bg) * 12544;
  float acc = dwb[c];
#pragma unroll
  for (int ky = 0; ky < 3; ky++) {
    int iy = qy * 2 - 1 + ky;
    if (iy < 0 || iy >= 112) continue;
#pragma unroll
    for (int kx = 0; kx < 3; kx++) {
      int ix = qx * 2 - 1 + kx;
      if (ix < 0 || ix >= 112) continue;
      acc += plane[iy * 112 + ix] * dw[c * 9 + ky * 3 + kx];
    }
  }
  h2[idx] = acc;
}

__global__ __launch_bounds__(256) void stem_pw(
    const float* __restrict__ h2, const float* __restrict__ w2, const float* __restrict__ b2,
    const float* __restrict__ g, const float* __restrict__ bb,
    const float* __restrict__ m, const float* __restrict__ v,
    float* __restrict__ H0) {
  int idx = blockIdx.x * 256 + threadIdx.x;       // ((o*G)+bg)*3136 + q
  int q = idx % N_HW;
  int t = idx / N_HW;
  int bg = t & (G - 1);
  int o = t >> 4;
  float acc = b2[o];
#pragma unroll
  for (int c = 0; c < 16; c++) acc += w2[o * 16 + c] * h2[(size_t)(c * G + bg) * N_HW + q];
  float y = (acc - m[o]) * (g[o] * rsqrtf(v[o] + EPS)) + bb[o];
  H0[idx] = y;
}

// ------- fused instance-norm stats + norm + relu + depthwise 3x3 (pad 1) -------
__global__ __launch_bounds__(256) void dw_fused(
    const float* __restrict__ base, const float* __restrict__ cdw,
    const float* __restrict__ in_g, const float* __restrict__ in_b,
    u16* __restrict__ XA, int cdwoff) {
  __shared__ float sm[58 * 58];
  __shared__ float red[256], red2[256];
  __shared__ float ssc, ssh;
  int blk = blockIdx.x;            // cl*G + bg
  int cl = blk >> 4;
  int c = cdwoff + cl;
  int tid = threadIdx.x;
  for (int i = tid; i < 58 * 58; i += 256) sm[i] = 0.f;
  __syncthreads();
  const float* row = base + (size_t)blk * N_HW;
  float s = 0.f, s2 = 0.f;
  for (int i = tid; i < N_HW; i += 256) {
    float xv = row[i];
    s += xv; s2 += xv * xv;
    int y = i / 56, x = i % 56;
    sm[(y + 1) * 58 + x + 1] = xv;
  }
  red[tid] = s; red2[tid] = s2;
  __syncthreads();
  for (int o = 128; o > 0; o >>= 1) {
    if (tid < o) { red[tid] += red[tid + o]; red2[tid] += red2[tid + o]; }
    __syncthreads();
  }
  if (tid == 0) {
    float mean = red[0] * (1.f / N_HW);
    float var = fmaxf(red2[0] * (1.f / N_HW) - mean * mean, 0.f);
    float sc = in_g[c] * rsqrtf(var + EPS);
    ssc = sc; ssh = in_b[c] - mean * sc;
  }
  __syncthreads();
  float sc = ssc, sh = ssh;
  for (int i = tid; i < N_HW; i += 256) {
    int y = i / 56, x = i % 56;
    int pos = (y + 1) * 58 + x + 1;
    sm[pos] = fmaxf(sm[pos] * sc + sh, 0.f);
  }
  __syncthreads();
  float w0 = cdw[c * 9 + 0], w1 = cdw[c * 9 + 1], w2 = cdw[c * 9 + 2];
  float w3 = cdw[c * 9 + 3], w4 = cdw[c * 9 + 4], w5 = cdw[c * 9 + 5];
  float w6 = cdw[c * 9 + 6], w7 = cdw[c * 9 + 7], w8 = cdw[c * 9 + 8];
  u16* outp = XA + (size_t)blk * N_HW;
  for (int i = tid; i < N_HW; i += 256) {
    int y = i / 56, x = i % 56;
    const float* p0 = &sm[y * 58 + x];
    float a = p0[0] * w0 + p0[1] * w1 + p0[2] * w2
            + p0[58] * w3 + p0[59] * w4 + p0[60] * w5
            + p0[116] * w6 + p0[117] * w7 + p0[118] * w8;
    outp[i] = f2b(a);
  }
}

// ---------------- MFMA GEMM: C[192][NG] = A[192][K] @ B[K][NG] (pure store) ----
// N-tile 64 (grid NG/64 = 784 ~ 3 blocks/CU), 4 waves 2x2, wave tile 96x32.
// Register-staged double-buffer, ONE barrier per K-tile: loads for t+1 issue
// before compute(t) and are written to LDS buf^1 after compute.
__global__ __launch_bounds__(256) void gemm_mfma(
    const u16* __restrict__ A, const u16* __restrict__ B, float* __restrict__ C, int K) {
  __shared__ u16 As[2][192][40];   // pitch 80 B (16B-aligned rows, conflict-free frags)
  __shared__ u16 Bs[2][32][64];    // pitch 128 B, XOR-16 column swizzle
  int n0 = blockIdx.x * 64;
  int tid = threadIdx.x;
  int wave = tid >> 6, lane = tid & 63;
  int wm = wave >> 1, wn = wave & 1;
  int lg = lane >> 4, li = lane & 15;
  floatx4 acc[6][2] = {};

  // staging thread map: A 192x32 as 3 chunks of 64 rows; B 32k x 64n, 1 uint4/thread
  int ar = tid >> 2, ak = (tid & 3) * 8;
  int bk = tid >> 3, bn = (tid & 7) * 8;
  int bnx = bn ^ ((bk >> 3) << 4);
  const u16* Ag = A + (size_t)ar * DIMC + ak;
  const u16* Bg = B + (size_t)bk * NG + n0 + bn;

  int nt = K / 32;
  // prologue: stage tile 0
  *(uint4*)&As[0][ar][ak]       = *(const uint4*)(Ag);
  *(uint4*)&As[0][ar + 64][ak]  = *(const uint4*)(Ag + (size_t)64 * DIMC);
  *(uint4*)&As[0][ar + 128][ak] = *(const uint4*)(Ag + (size_t)128 * DIMC);
  *(uint4*)&Bs[0][bk][bnx]      = *(const uint4*)(Bg);
  __syncthreads();

  int cur = 0;
  for (int t = 0; t < nt; t++) {
    uint4 ra0, ra1, ra2, rb;
    bool pf = (t + 1 < nt);
    if (pf) {                                   // issue next-tile loads early
      const u16* ag = Ag + (size_t)(t + 1) * 32;
      ra0 = *(const uint4*)(ag);
      ra1 = *(const uint4*)(ag + (size_t)64 * DIMC);
      ra2 = *(const uint4*)(ag + (size_t)128 * DIMC);
      rb  = *(const uint4*)(Bg + (size_t)(t + 1) * 32 * NG);
    }
    // compute on buf[cur] (loads in flight hide under MFMA)
    short8 aF[6];
#pragma unroll
    for (int mi = 0; mi < 6; mi++)
      aF[mi] = *(const short8*)&As[cur][wm * 96 + mi * 16 + li][lg * 8];
#pragma unroll
    for (int ni = 0; ni < 2; ni++) {
      int colx = ((wn * 32 + ni * 16) ^ (lg << 4)) + li;
      short8 bF;
#pragma unroll
      for (int e = 0; e < 8; e++) bF[e] = (short)Bs[cur][lg * 8 + e][colx];
#pragma unroll
      for (int mi = 0; mi < 6; mi++)
        acc[mi][ni] = __builtin_amdgcn_mfma_f32_16x16x32_bf16(aF[mi], bF, acc[mi][ni], 0, 0, 0);
    }
    if (pf) {                                   // write staged regs -> buf^1
      *(uint4*)&As[cur ^ 1][ar][ak]       = ra0;
      *(uint4*)&As[cur ^ 1][ar + 64][ak]  = ra1;
      *(uint4*)&As[cur ^ 1][ar + 128][ak] = ra2;
      *(uint4*)&Bs[cur ^ 1][bk][bnx]      = rb;
    }
    __syncthreads();                            // single barrier per K-tile
    cur ^= 1;
  }

#pragma unroll
  for (int mi = 0; mi < 6; mi++) {
#pragma unroll
    for (int ni = 0; ni < 2; ni++) {
      int row = wm * 96 + mi * 16 + lg * 4;     // C/D: col=lane&15, row=lg*4+r
      int col = n0 + wn * 32 + ni * 16 + li;
      float* cp = C + (size_t)row * NG + col;
#pragma unroll
      for (int r = 0; r < 4; r++) cp[(size_t)r * NG] = acc[mi][ni][r];
    }
  }
}

// ------- head: layer-4 stats + norm + dwconv on 2x2 patch, per (c,bg) block -------
__global__ __launch_bounds__(256) void head_m4(
    const float* __restrict__ HT, const float* __restrict__ in_g, const float* __restrict__ in_b,
    const float* __restrict__ cdw, float* __restrict__ m4, float* __restrict__ meanH) {
  int blk = blockIdx.x;            // cl*G + bg, cl in [0,192)
  int cl = blk >> 4;
  int c = 608 + cl;
  int tid = threadIdx.x;
  const float* row = HT + (size_t)blk * N_HW;
  float s = 0.f, s2 = 0.f;
  for (int i = tid; i < N_HW; i += 256) {
    float xv = row[i];
    s += xv; s2 += xv * xv;
  }
  __shared__ float red[256], red2[256];
  red[tid] = s; red2[tid] = s2;
  __syncthreads();
  for (int o = 128; o > 0; o >>= 1) {
    if (tid < o) { red[tid] += red[tid + o]; red2[tid] += red2[tid + o]; }
    __syncthreads();
  }
  if (tid == 0) {
    float mean = red[0] * (1.f / N_HW);
    float var = fmaxf(red2[0] * (1.f / N_HW) - mean * mean, 0.f);
    float sc = in_g[c] * rsqrtf(var + EPS);
    float sh = in_b[c] - mean * sc;
    float val[4][4];
#pragma unroll
    for (int dy = 0; dy < 4; dy++)
#pragma unroll
      for (int dx = 0; dx < 4; dx++)
        val[dy][dx] = fmaxf(row[(25 + dy) * 56 + 25 + dx] * sc + sh, 0.f);
    const float* w = cdw + c * 9;
    float acc = 0.f;
#pragma unroll
    for (int oy = 1; oy < 3; oy++)
#pragma unroll
      for (int ox = 1; ox < 3; ox++)
#pragma unroll
        for (int ky = 0; ky < 3; ky++)
#pragma unroll
          for (int kx = 0; kx < 3; kx++)
            acc += val[oy + ky - 1][ox + kx - 1] * w[ky * 3 + kx];
    m4[blk] = acc * 0.25f;
    meanH[blk] = 0.25f * (row[26 * 56 + 26] + row[26 * 56 + 27] +
                          row[27 * 56 + 26] + row[27 * 56 + 27]);
  }
}

__global__ __launch_bounds__(256) void head_mix(
    const float* __restrict__ gw, const float* __restrict__ m4, const float* __restrict__ meanH,
    float* __restrict__ out_pre) {
  int idx = blockIdx.x * 256 + threadIdx.x;   // bg*192 + j
  if (idx >= G * 192) return;
  int j = idx % 192;
  int bg = idx / 192;
  float acc = meanH[j * G + bg];
  const float* grow = gw + (size_t)(608 + j) * DIMC + 608;
  for (int c = 0; c < 192; c++) acc += grow[c] * m4[c * G + bg];
  out_pre[idx] = acc;
}

__global__ __launch_bounds__(256) void head_fc(
    const float* __restrict__ out_pre, const float* __restrict__ fc_w,
    const float* __restrict__ fc_b, float* __restrict__ outg) {
  int idx = blockIdx.x * 256 + threadIdx.x;   // bg*1000 + t
  if (idx >= G * 1000) return;
  int t = idx % 1000;
  int bg = idx / 1000;
  float acc = fc_b[t];
  const float* wr = fc_w + (size_t)t * 192;
  const float* hr = out_pre + (size_t)bg * 192;
  for (int j = 0; j < 192; j++) acc += wr[j] * hr[j];
  outg[idx] = acc;
}

extern "C" void kernel_launch(void* const* d_in, const int* in_sizes, int n_in,
                              void* d_out, int out_size, void* d_ws, size_t ws_size,
                              hipStream_t stream) {
  const float* x      = (const float*)d_in[0];
  const float* ds_w1  = (const float*)d_in[1];
  const float* ds_b1  = (const float*)d_in[2];
  const float* bn1_g  = (const float*)d_in[3];
  const float* bn1_b  = (const float*)d_in[4];
  const float* bn1_m  = (const float*)d_in[5];
  const float* bn1_v  = (const float*)d_in[6];
  const float* ds_dw  = (const float*)d_in[7];
  const float* ds_dwb = (const float*)d_in[8];
  const float* ds_w2  = (const float*)d_in[9];
  const float* ds_b2  = (const float*)d_in[10];
  const float* bn2_g  = (const float*)d_in[11];
  const float* bn2_b  = (const float*)d_in[12];
  const float* bn2_m  = (const float*)d_in[13];
  const float* bn2_v  = (const float*)d_in[14];
  const float* cdw    = (const float*)d_in[15];
  const float* gw     = (const float*)d_in[16];
  const float* in_g   = (const float*)d_in[17];
  const float* in_b   = (const float*)d_in[18];
  const float* fc_w   = (const float*)d_in[19];
  const float* fc_b   = (const float*)d_in[20];
  float* out = (float*)d_out;
  char* ws = (char*)d_ws;

  if (ws_size < NEED) return;

  u16*   XAc   = (u16*)(ws + XA_OFF);
  float* H0    = (float*)(ws + H0_OFF);
  float* block = (float*)(ws + BLK_OFF);
  u16*   gwb   = (u16*)(ws + GWB_OFF);
  float* m4    = (float*)(ws + M4_OFF);
  float* meanH = (float*)(ws + MH_OFF);
  float* opre  = (float*)(ws + OP_OFF);
  float* h1    = block;                             // 12.85 MB, dead after stem
  float* h2    = block + (size_t)16 * G * 12544;    // 3.2 MB

  gw2bf<<<625, 256, 0, stream>>>(gw, gwb);

  static const int CDWOFF[4] = {0, 32, 224, 416};   // dw layer channel base
  static const int SZ[4]     = {32, 192, 192, 192};
  static const int RA[4]     = {32, 224, 416, 608}; // gemm output channel base
  static const int KK[4]     = {32, 224, 416, 608};

  for (int g = 0; g < 32 / G; g++) {
    const float* xg = x + (size_t)g * G * 3 * 224 * 224;

    stem_conv1<<<14 * G, 256, 0, stream>>>(
        xg, ds_w1, ds_b1, bn1_g, bn1_b, bn1_m, bn1_v, h1);
    stem_dw<<<16 * G * N_HW / 256, 256, 0, stream>>>(h1, ds_dw, ds_dwb, h2);
    stem_pw<<<32 * G * N_HW / 256, 256, 0, stream>>>(
        h2, ds_w2, ds_b2, bn2_g, bn2_b, bn2_m, bn2_v, H0);

    for (int i = 0; i < 4; i++) {
      const float* in = (i == 0) ? H0 : block;
      dw_fused<<<SZ[i] * G, 256, 0, stream>>>(
          in, cdw, in_g, in_b, XAc + (size_t)CDWOFF[i] * NG, CDWOFF[i]);
      gemm_mfma<<<NG / 64, 256, 0, stream>>>(gwb + (size_t)RA[i] * DIMC, XAc, block, KK[i]);
    }

    head_m4<<<192 * G, 256, 0, stream>>>(block, in_g, in_b, cdw, m4, meanH);
    head_mix<<<(G * 192 + 255) / 256, 256, 0, stream>>>(gw, m4, meanH, opre);
    head_fc<<<(G * 1000 + 255) / 256, 256, 0, stream>>>(opre, fc_w, fc_b, out + (size_t)g * G * 1000);
  }
}

// Round 10
// 428.717 us; speedup vs baseline: 2.4314x; 1.0855x over previous
//
#include <hip/hip_runtime.h>
#include <stddef.h>

#define EPS 1e-5f
#define N_HW 3136              // 56*56
#define G 16                   // batches per group (2 groups of 16)
#define NG (G * N_HW)          // 50176 = group GEMM N dimension
#define DIMC 800

typedef unsigned short u16;
typedef __attribute__((ext_vector_type(8))) short short8;
typedef __attribute__((ext_vector_type(4))) float floatx4;

__device__ __forceinline__ u16 f2b(float f) {
  unsigned u = __float_as_uint(f);
  u += 0x7FFFu + ((u >> 16) & 1u);        // round-to-nearest-even
  return (u16)(u >> 16);
}
__device__ __forceinline__ float blo(unsigned u) { return __uint_as_float(u << 16); }
__device__ __forceinline__ float bhi(unsigned u) { return __uint_as_float(u & 0xFFFF0000u); }

// ---------------- ws layout (bytes) ----------------
// XA_cat : bf16 [608][NG] = 61,014,016
// H0     : f32  [32][NG]  =  6,422,528
// block  : 38.5 MB region; L0-L2 gemm out bf16 [192][NG], L3 out f32 [192][NG]
//          (stem h1/h2 alias inside; all uses sequential)
// gwb    : bf16 [800][800]; smalls after
static const size_t XA_OFF  = 0;
static const size_t H0_OFF  = 61014016ull;
static const size_t BLK_OFF = 67436544ull;
static const size_t GWB_OFF = 105971712ull;
static const size_t M4_OFF  = 107251712ull;
static const size_t MH_OFF  = M4_OFF + 192 * G * 4;
static const size_t OP_OFF  = MH_OFF + 192 * G * 4;
static const size_t NEED    = OP_OFF + (size_t)G * 192 * 4;   // ~107.3 MB

// ---------------- gw -> bf16 ----------------
__global__ __launch_bounds__(256) void gw2bf(const float* __restrict__ gw, u16* __restrict__ gwb) {
  int i = (blockIdx.x * 256 + threadIdx.x) * 4;   // 640000 elems, 625 blocks
  float4 v = *(const float4*)(gw + i);
  gwb[i + 0] = f2b(v.x); gwb[i + 1] = f2b(v.y);
  gwb[i + 2] = f2b(v.z); gwb[i + 3] = f2b(v.w);
}

// ---------------- stem conv1: LDS-tiled, all 16 ch per block ----------------
#define XT_PITCH 226
#define XT_CH (17 * XT_PITCH)          // 3842
__global__ __launch_bounds__(256) void stem_conv1(
    const float* __restrict__ xg, const float* __restrict__ w, const float* __restrict__ b1,
    const float* __restrict__ g, const float* __restrict__ bb,
    const float* __restrict__ m, const float* __restrict__ v,
    float* __restrict__ h1) {
  __shared__ float xt[3 * XT_CH];      // 46.1 KB
  __shared__ float wt[16 * 27];
  __shared__ float mulc[16], addc[16];
  int blk = blockIdx.x;                // s + 14*bg
  int s = blk % 14;
  int bg = blk / 14;
  int tid = threadIdx.x;

  for (int e = tid; e < 432; e += 256) wt[e] = w[e];
  if (tid < 16) {
    float A = g[tid] * rsqrtf(v[tid] + EPS);
    mulc[tid] = A;
    addc[tid] = (b1[tid] - m[tid]) * A + bb[tid];
  }
  int iy0 = 16 * s - 1;
  for (int e = tid; e < 3 * XT_CH; e += 256) {
    int ci = e / XT_CH;
    int rem = e - ci * XT_CH;
    int r = rem / XT_PITCH;
    int cc = rem - r * XT_PITCH;
    int iy = iy0 + r, ix = cc - 1;
    float val = 0.f;
    if (iy >= 0 && iy < 224 && ix >= 0 && ix < 224)
      val = xg[((size_t)(bg * 3 + ci)) * 224 * 224 + iy * 224 + ix];
    xt[e] = val;
  }
  __syncthreads();

  for (int p = tid; p < 8 * 112; p += 256) {
    int oyl = p / 112, ox = p - oyl * 112;
    float xv[27];
#pragma unroll
    for (int ci = 0; ci < 3; ci++)
#pragma unroll
      for (int ky = 0; ky < 3; ky++)
#pragma unroll
        for (int kx = 0; kx < 3; kx++)
          xv[ci * 9 + ky * 3 + kx] = xt[ci * XT_CH + (2 * oyl + ky) * XT_PITCH + 2 * ox + kx];
    int oy = 8 * s + oyl;
#pragma unroll
    for (int c = 0; c < 16; c++) {
      float acc = 0.f;
#pragma unroll
      for (int t = 0; t < 27; t++) acc += xv[t] * wt[c * 27 + t];
      float y = acc * mulc[c] + addc[c];
      h1[(size_t)(c * G + bg) * 12544 + oy * 112 + ox] = fmaxf(y, 0.f);
    }
  }
}

__global__ __launch_bounds__(256) void stem_dw(
    const float* __restrict__ h1, const float* __restrict__ dw, const float* __restrict__ dwb,
    float* __restrict__ h2) {
  int idx = blockIdx.x * 256 + threadIdx.x;       // ((c*G)+bg)*3136 + q
  int q = idx % N_HW;
  int t = idx / N_HW;
  int bg = t & (G - 1);
  int c = t >> 4;
  int qy = q / 56, qx = q % 56;
  const float* plane = h1 + (size_t)(c * G + bg) * 12544;
  float acc = dwb[c];
#pragma unroll
  for (int ky = 0; ky < 3; ky++) {
    int iy = qy * 2 - 1 + ky;
    if (iy < 0 || iy >= 112) continue;
#pragma unroll
    for (int kx = 0; kx < 3; kx++) {
      int ix = qx * 2 - 1 + kx;
      if (ix < 0 || ix >= 112) continue;
      acc += plane[iy * 112 + ix] * dw[c * 9 + ky * 3 + kx];
    }
  }
  h2[idx] = acc;
}

__global__ __launch_bounds__(256) void stem_pw(
    const float* __restrict__ h2, const float* __restrict__ w2, const float* __restrict__ b2,
    const float* __restrict__ g, const float* __restrict__ bb,
    const float* __restrict__ m, const float* __restrict__ v,
    float* __restrict__ H0) {
  int idx = blockIdx.x * 256 + threadIdx.x;       // ((o*G)+bg)*3136 + q
  int q = idx % N_HW;
  int t = idx / N_HW;
  int bg = t & (G - 1);
  int o = t >> 4;
  float acc = b2[o];
#pragma unroll
  for (int c = 0; c < 16; c++) acc += w2[o * 16 + c] * h2[(size_t)(c * G + bg) * N_HW + q];
  float y = (acc - m[o]) * (g[o] * rsqrtf(v[o] + EPS)) + bb[o];
  H0[idx] = y;
}

// ------- fused instance-norm stats + norm + relu + depthwise 3x3 (pad 1) -------
// vectorized loads (8 elem/iter, no row straddle: 56%8==0), halo-only init,
// wave-shfl reduction (3 barriers), paired bf16 stores. T = float or u16(bf16).
template <typename T>
__global__ __launch_bounds__(256) void dw_fused(
    const T* __restrict__ base, const float* __restrict__ cdw,
    const float* __restrict__ in_g, const float* __restrict__ in_b,
    u16* __restrict__ XA, int cdwoff) {
  __shared__ float sm[58 * 58];
  __shared__ float wred[8];
  int blk = blockIdx.x;            // cl*G + bg
  int cl = blk >> 4;
  int c = cdwoff + cl;
  int tid = threadIdx.x;

  // halo-only zero init (rows 0,57; cols 0,57 of rows 1..56)
  if (tid < 58) { sm[tid] = 0.f; sm[57 * 58 + tid] = 0.f; }
  if (tid >= 64 && tid < 120) { int r = tid - 63; sm[r * 58] = 0.f; sm[r * 58 + 57] = 0.f; }

  const T* row = base + (size_t)blk * N_HW;
  float s = 0.f, s2 = 0.f;
  for (int i = tid; i < 392; i += 256) {
    float vals[8];
    if constexpr (sizeof(T) == 2) {
      uint4 u = *(const uint4*)((const u16*)row + i * 8);
      vals[0] = blo(u.x); vals[1] = bhi(u.x);
      vals[2] = blo(u.y); vals[3] = bhi(u.y);
      vals[4] = blo(u.z); vals[5] = bhi(u.z);
      vals[6] = blo(u.w); vals[7] = bhi(u.w);
    } else {
      float4 v0 = *(const float4*)((const float*)row + i * 8);
      float4 v1 = *(const float4*)((const float*)row + i * 8 + 4);
      vals[0] = v0.x; vals[1] = v0.y; vals[2] = v0.z; vals[3] = v0.w;
      vals[4] = v1.x; vals[5] = v1.y; vals[6] = v1.z; vals[7] = v1.w;
    }
    int p = i * 8;
    int y = p / 56, x = p - y * 56;
    float* d = &sm[(y + 1) * 58 + x + 1];
#pragma unroll
    for (int e = 0; e < 8; e++) {
      d[e] = vals[e];
      s += vals[e];
      s2 += vals[e] * vals[e];
    }
  }
#pragma unroll
  for (int o = 32; o > 0; o >>= 1) {
    s += __shfl_down(s, o);
    s2 += __shfl_down(s2, o);
  }
  if ((tid & 63) == 0) { wred[(tid >> 6) * 2] = s; wred[(tid >> 6) * 2 + 1] = s2; }
  __syncthreads();
  float ts = (wred[0] + wred[2]) + (wred[4] + wred[6]);
  float tq = (wred[1] + wred[3]) + (wred[5] + wred[7]);
  float mean = ts * (1.f / N_HW);
  float var = fmaxf(tq * (1.f / N_HW) - mean * mean, 0.f);
  float sc = in_g[c] * rsqrtf(var + EPS);
  float sh = in_b[c] - mean * sc;

  // norm+relu in place (interior only; halo stays 0)
  for (int i = tid; i < N_HW; i += 256) {
    int y = i / 56, x = i - y * 56;
    int pos = (y + 1) * 58 + x + 1;
    sm[pos] = fmaxf(sm[pos] * sc + sh, 0.f);
  }
  __syncthreads();

  float w0 = cdw[c * 9 + 0], w1 = cdw[c * 9 + 1], w2 = cdw[c * 9 + 2];
  float w3 = cdw[c * 9 + 3], w4 = cdw[c * 9 + 4], w5 = cdw[c * 9 + 5];
  float w6 = cdw[c * 9 + 6], w7 = cdw[c * 9 + 7], w8 = cdw[c * 9 + 8];
  u16* outp = XA + (size_t)blk * N_HW;
  for (int pp = tid; pp < N_HW / 2; pp += 256) {   // pairs (56 even -> same row)
    int p = pp * 2;
    int y = p / 56, x = p - y * 56;
    const float* p0 = &sm[y * 58 + x];
    float a0 = p0[0] * w0 + p0[1] * w1 + p0[2] * w2
             + p0[58] * w3 + p0[59] * w4 + p0[60] * w5
             + p0[116] * w6 + p0[117] * w7 + p0[118] * w8;
    float a1 = p0[1] * w0 + p0[2] * w1 + p0[3] * w2
             + p0[59] * w3 + p0[60] * w4 + p0[61] * w5
             + p0[117] * w6 + p0[118] * w7 + p0[119] * w8;
    unsigned pk = (unsigned)f2b(a0) | ((unsigned)f2b(a1) << 16);
    *(unsigned*)&outp[p] = pk;
  }
}

// ---------------- MFMA GEMM: C[192][NG] = A[192][K] @ B[K][NG] (pure store) ----
// r8 known-good structure: N-tile 64, 4 waves 2x2, wave tile 96x32,
// register-staged double-buffer, one barrier per K-tile, scalar B-gather
// from XOR-16 swizzled LDS. Templated on C store type (f32 or bf16).
template <typename TC>
__global__ __launch_bounds__(256) void gemm_mfma(
    const u16* __restrict__ A, const u16* __restrict__ B, TC* __restrict__ C, int K) {
  __shared__ u16 As[2][192][40];   // pitch 80 B
  __shared__ u16 Bs[2][32][64];    // pitch 128 B, XOR-16 column swizzle
  int n0 = blockIdx.x * 64;
  int tid = threadIdx.x;
  int wave = tid >> 6, lane = tid & 63;
  int wm = wave >> 1, wn = wave & 1;
  int lg = lane >> 4, li = lane & 15;
  floatx4 acc[6][2] = {};

  int ar = tid >> 2, ak = (tid & 3) * 8;
  int bk = tid >> 3, bn = (tid & 7) * 8;
  int bnx = bn ^ ((bk >> 3) << 4);
  const u16* Ag = A + (size_t)ar * DIMC + ak;
  const u16* Bg = B + (size_t)bk * NG + n0 + bn;

  int nt = K / 32;
  *(uint4*)&As[0][ar][ak]       = *(const uint4*)(Ag);
  *(uint4*)&As[0][ar + 64][ak]  = *(const uint4*)(Ag + (size_t)64 * DIMC);
  *(uint4*)&As[0][ar + 128][ak] = *(const uint4*)(Ag + (size_t)128 * DIMC);
  *(uint4*)&Bs[0][bk][bnx]      = *(const uint4*)(Bg);
  __syncthreads();

  int cur = 0;
  for (int t = 0; t < nt; t++) {
    uint4 ra0, ra1, ra2, rb;
    bool pf = (t + 1 < nt);
    if (pf) {                                   // issue next-tile loads early
      const u16* ag = Ag + (size_t)(t + 1) * 32;
      ra0 = *(const uint4*)(ag);
      ra1 = *(const uint4*)(ag + (size_t)64 * DIMC);
      ra2 = *(const uint4*)(ag + (size_t)128 * DIMC);
      rb  = *(const uint4*)(Bg + (size_t)(t + 1) * 32 * NG);
    }
    short8 aF[6];
#pragma unroll
    for (int mi = 0; mi < 6; mi++)
      aF[mi] = *(const short8*)&As[cur][wm * 96 + mi * 16 + li][lg * 8];
#pragma unroll
    for (int ni = 0; ni < 2; ni++) {
      int colx = ((wn * 32 + ni * 16) ^ (lg << 4)) + li;
      short8 bF;
#pragma unroll
      for (int e = 0; e < 8; e++) bF[e] = (short)Bs[cur][lg * 8 + e][colx];
#pragma unroll
      for (int mi = 0; mi < 6; mi++)
        acc[mi][ni] = __builtin_amdgcn_mfma_f32_16x16x32_bf16(aF[mi], bF, acc[mi][ni], 0, 0, 0);
    }
    if (pf) {
      *(uint4*)&As[cur ^ 1][ar][ak]       = ra0;
      *(uint4*)&As[cur ^ 1][ar + 64][ak]  = ra1;
      *(uint4*)&As[cur ^ 1][ar + 128][ak] = ra2;
      *(uint4*)&Bs[cur ^ 1][bk][bnx]      = rb;
    }
    __syncthreads();
    cur ^= 1;
  }

#pragma unroll
  for (int mi = 0; mi < 6; mi++) {
#pragma unroll
    for (int ni = 0; ni < 2; ni++) {
      int row = wm * 96 + mi * 16 + lg * 4;     // C/D: col=lane&15, row=lg*4+r
      int col = n0 + wn * 32 + ni * 16 + li;
      TC* cp = C + (size_t)row * NG + col;
#pragma unroll
      for (int r = 0; r < 4; r++) {
        if constexpr (sizeof(TC) == 2) cp[(size_t)r * NG] = f2b(acc[mi][ni][r]);
        else                           cp[(size_t)r * NG] = acc[mi][ni][r];
      }
    }
  }
}

// ------- head: layer-4 stats + norm + dwconv on 2x2 patch, per (c,bg) block -------
__global__ __launch_bounds__(256) void head_m4(
    const float* __restrict__ HT, const float* __restrict__ in_g, const float* __restrict__ in_b,
    const float* __restrict__ cdw, float* __restrict__ m4, float* __restrict__ meanH) {
  int blk = blockIdx.x;            // cl*G + bg, cl in [0,192)
  int cl = blk >> 4;
  int c = 608 + cl;
  int tid = threadIdx.x;
  const float* row = HT + (size_t)blk * N_HW;
  float s = 0.f, s2 = 0.f;
  for (int i = tid; i < N_HW; i += 256) {
    float xv = row[i];
    s += xv; s2 += xv * xv;
  }
  __shared__ float red[256], red2[256];
  red[tid] = s; red2[tid] = s2;
  __syncthreads();
  for (int o = 128; o > 0; o >>= 1) {
    if (tid < o) { red[tid] += red[tid + o]; red2[tid] += red2[tid + o]; }
    __syncthreads();
  }
  if (tid == 0) {
    float mean = red[0] * (1.f / N_HW);
    float var = fmaxf(red2[0] * (1.f / N_HW) - mean * mean, 0.f);
    float sc = in_g[c] * rsqrtf(var + EPS);
    float sh = in_b[c] - mean * sc;
    float val[4][4];
#pragma unroll
    for (int dy = 0; dy < 4; dy++)
#pragma unroll
      for (int dx = 0; dx < 4; dx++)
        val[dy][dx] = fmaxf(row[(25 + dy) * 56 + 25 + dx] * sc + sh, 0.f);
    const float* w = cdw + c * 9;
    float acc = 0.f;
#pragma unroll
    for (int oy = 1; oy < 3; oy++)
#pragma unroll
      for (int ox = 1; ox < 3; ox++)
#pragma unroll
        for (int ky = 0; ky < 3; ky++)
#pragma unroll
          for (int kx = 0; kx < 3; kx++)
            acc += val[oy + ky - 1][ox + kx - 1] * w[ky * 3 + kx];
    m4[blk] = acc * 0.25f;
    meanH[blk] = 0.25f * (row[26 * 56 + 26] + row[26 * 56 + 27] +
                          row[27 * 56 + 26] + row[27 * 56 + 27]);
  }
}

__global__ __launch_bounds__(256) void head_mix(
    const float* __restrict__ gw, const float* __restrict__ m4, const float* __restrict__ meanH,
    float* __restrict__ out_pre) {
  int idx = blockIdx.x * 256 + threadIdx.x;   // bg*192 + j
  if (idx >= G * 192) return;
  int j = idx % 192;
  int bg = idx / 192;
  float acc = meanH[j * G + bg];
  const float* grow = gw + (size_t)(608 + j) * DIMC + 608;
  for (int c = 0; c < 192; c++) acc += grow[c] * m4[c * G + bg];
  out_pre[idx] = acc;
}

__global__ __launch_bounds__(256) void head_fc(
    const float* __restrict__ out_pre, const float* __restrict__ fc_w,
    const float* __restrict__ fc_b, float* __restrict__ outg) {
  int idx = blockIdx.x * 256 + threadIdx.x;   // bg*1000 + t
  if (idx >= G * 1000) return;
  int t = idx % 1000;
  int bg = idx / 1000;
  float acc = fc_b[t];
  const float* wr = fc_w + (size_t)t * 192;
  const float* hr = out_pre + (size_t)bg * 192;
  for (int j = 0; j < 192; j++) acc += wr[j] * hr[j];
  outg[idx] = acc;
}

extern "C" void kernel_launch(void* const* d_in, const int* in_sizes, int n_in,
                              void* d_out, int out_size, void* d_ws, size_t ws_size,
                              hipStream_t stream) {
  const float* x      = (const float*)d_in[0];
  const float* ds_w1  = (const float*)d_in[1];
  const float* ds_b1  = (const float*)d_in[2];
  const float* bn1_g  = (const float*)d_in[3];
  const float* bn1_b  = (const float*)d_in[4];
  const float* bn1_m  = (const float*)d_in[5];
  const float* bn1_v  = (const float*)d_in[6];
  const float* ds_dw  = (const float*)d_in[7];
  const float* ds_dwb = (const float*)d_in[8];
  const float* ds_w2  = (const float*)d_in[9];
  const float* ds_b2  = (const float*)d_in[10];
  const float* bn2_g  = (const float*)d_in[11];
  const float* bn2_b  = (const float*)d_in[12];
  const float* bn2_m  = (const float*)d_in[13];
  const float* bn2_v  = (const float*)d_in[14];
  const float* cdw    = (const float*)d_in[15];
  const float* gw     = (const float*)d_in[16];
  const float* in_g   = (const float*)d_in[17];
  const float* in_b   = (const float*)d_in[18];
  const float* fc_w   = (const float*)d_in[19];
  const float* fc_b   = (const float*)d_in[20];
  float* out = (float*)d_out;
  char* ws = (char*)d_ws;

  if (ws_size < NEED) return;

  u16*   XAc    = (u16*)(ws + XA_OFF);
  float* H0     = (float*)(ws + H0_OFF);
  u16*   blockb = (u16*)(ws + BLK_OFF);     // L0-L2 gemm out (bf16)
  float* blockf = (float*)(ws + BLK_OFF);   // L3 gemm out (f32), aliases blockb (dead)
  u16*   gwb    = (u16*)(ws + GWB_OFF);
  float* m4     = (float*)(ws + M4_OFF);
  float* meanH  = (float*)(ws + MH_OFF);
  float* opre   = (float*)(ws + OP_OFF);
  float* h1     = (float*)(ws + BLK_OFF);   // stem temps alias block region
  float* h2     = h1 + (size_t)16 * G * 12544;

  gw2bf<<<625, 256, 0, stream>>>(gw, gwb);

  static const int CDWOFF[4] = {0, 32, 224, 416};   // dw layer channel base
  static const int SZ[4]     = {32, 192, 192, 192};
  static const int RA[4]     = {32, 224, 416, 608}; // gemm output channel base
  static const int KK[4]     = {32, 224, 416, 608};

  for (int g = 0; g < 32 / G; g++) {
    const float* xg = x + (size_t)g * G * 3 * 224 * 224;

    stem_conv1<<<14 * G, 256, 0, stream>>>(
        xg, ds_w1, ds_b1, bn1_g, bn1_b, bn1_m, bn1_v, h1);
    stem_dw<<<16 * G * N_HW / 256, 256, 0, stream>>>(h1, ds_dw, ds_dwb, h2);
    stem_pw<<<32 * G * N_HW / 256, 256, 0, stream>>>(
        h2, ds_w2, ds_b2, bn2_g, bn2_b, bn2_m, bn2_v, H0);

    for (int i = 0; i < 4; i++) {
      if (i == 0)
        dw_fused<float><<<SZ[i] * G, 256, 0, stream>>>(
            H0, cdw, in_g, in_b, XAc + (size_t)CDWOFF[i] * NG, CDWOFF[i]);
      else
        dw_fused<u16><<<SZ[i] * G, 256, 0, stream>>>(
            blockb, cdw, in_g, in_b, XAc + (size_t)CDWOFF[i] * NG, CDWOFF[i]);
      if (i < 3)
        gemm_mfma<u16><<<NG / 64, 256, 0, stream>>>(
            gwb + (size_t)RA[i] * DIMC, XAc, blockb, KK[i]);
      else
        gemm_mfma<float><<<NG / 64, 256, 0, stream>>>(
            gwb + (size_t)RA[i] * DIMC, XAc, blockf, KK[i]);
    }

    head_m4<<<192 * G, 256, 0, stream>>>(blockf, in_g, in_b, cdw, m4, meanH);
    head_mix<<<(G * 192 + 255) / 256, 256, 0, stream>>>(gw, m4, meanH, opre);
    head_fc<<<(G * 1000 + 255) / 256, 256, 0, stream>>>(opre, fc_w, fc_b, out + (size_t)g * G * 1000);
  }
}

// Round 11
// 392.178 us; speedup vs baseline: 2.6580x; 1.0932x over previous
//
#include <hip/hip_runtime.h>
#include <stddef.h>

#define EPS 1e-5f
#define N_HW 3136              // 56*56
#define G 32                   // full batch, single pass
#define NG (G * N_HW)          // 100352 = GEMM N dimension
#define DIMC 800
#define NTILE 49               // 3136/64: 64-col tiles per image

typedef unsigned short u16;
typedef __attribute__((ext_vector_type(8))) short short8;
typedef __attribute__((ext_vector_type(4))) float floatx4;

__device__ __forceinline__ u16 f2b(float f) {
  unsigned u = __float_as_uint(f);
  u += 0x7FFFu + ((u >> 16) & 1u);        // round-to-nearest-even
  return (u16)(u >> 16);
}
__device__ __forceinline__ float blo(unsigned u) { return __uint_as_float(u << 16); }
__device__ __forceinline__ float bhi(unsigned u) { return __uint_as_float(u & 0xFFFF0000u); }

// ---------------- ws layout (bytes) ----------------
// XA_cat : bf16 [608][NG] = 122,028,032
// H0     : f32  [32][NG]  =  12,845,056
// blockb : bf16 [192][NG] =  38,535,168  (L0-L2 gemm out; stem h1/h2 alias)
// gwb    : bf16 800x800   =   1,280,000
// statS/statQ: f32 6144 each; patchf: f32 [192][32][192] = 4,718,592
static const size_t XA_OFF  = 0;
static const size_t H0_OFF  = 122028032ull;
static const size_t BLK_OFF = 134873088ull;
static const size_t GWB_OFF = 173408256ull;
static const size_t STS_OFF = 174688256ull;
static const size_t STQ_OFF = 174712832ull;
static const size_t PAT_OFF = 174737408ull;
static const size_t M4_OFF  = 179456000ull;
static const size_t MH_OFF  = M4_OFF + 6144 * 4;
static const size_t OP_OFF  = MH_OFF + 6144 * 4;
static const size_t NEED    = OP_OFF + 6144 * 4;   // ~179.5 MB

// ---------------- small utility kernels ----------------
__global__ __launch_bounds__(256) void gw2bf(const float* __restrict__ gw, u16* __restrict__ gwb) {
  int i = (blockIdx.x * 256 + threadIdx.x) * 4;   // 640000 elems, 625 blocks
  float4 v = *(const float4*)(gw + i);
  gwb[i + 0] = f2b(v.x); gwb[i + 1] = f2b(v.y);
  gwb[i + 2] = f2b(v.z); gwb[i + 3] = f2b(v.w);
}

__global__ __launch_bounds__(256) void zero_stats(float* __restrict__ p) {
  p[blockIdx.x * 256 + threadIdx.x] = 0.f;        // 12288 floats, 48 blocks
}

// ---------------- stem conv1: LDS-tiled, all 16 ch per block ----------------
#define XT_PITCH 226
#define XT_CH (17 * XT_PITCH)          // 3842
__global__ __launch_bounds__(256) void stem_conv1(
    const float* __restrict__ xg, const float* __restrict__ w, const float* __restrict__ b1,
    const float* __restrict__ g, const float* __restrict__ bb,
    const float* __restrict__ m, const float* __restrict__ v,
    float* __restrict__ h1) {
  __shared__ float xt[3 * XT_CH];      // 46.1 KB
  __shared__ float wt[16 * 27];
  __shared__ float mulc[16], addc[16];
  int blk = blockIdx.x;                // s + 14*bg
  int s = blk % 14;
  int bg = blk / 14;
  int tid = threadIdx.x;

  for (int e = tid; e < 432; e += 256) wt[e] = w[e];
  if (tid < 16) {
    float A = g[tid] * rsqrtf(v[tid] + EPS);
    mulc[tid] = A;
    addc[tid] = (b1[tid] - m[tid]) * A + bb[tid];
  }
  int iy0 = 16 * s - 1;
  for (int e = tid; e < 3 * XT_CH; e += 256) {
    int ci = e / XT_CH;
    int rem = e - ci * XT_CH;
    int r = rem / XT_PITCH;
    int cc = rem - r * XT_PITCH;
    int iy = iy0 + r, ix = cc - 1;
    float val = 0.f;
    if (iy >= 0 && iy < 224 && ix >= 0 && ix < 224)
      val = xg[((size_t)(bg * 3 + ci)) * 224 * 224 + iy * 224 + ix];
    xt[e] = val;
  }
  __syncthreads();

  for (int p = tid; p < 8 * 112; p += 256) {
    int oyl = p / 112, ox = p - oyl * 112;
    float xv[27];
#pragma unroll
    for (int ci = 0; ci < 3; ci++)
#pragma unroll
      for (int ky = 0; ky < 3; ky++)
#pragma unroll
        for (int kx = 0; kx < 3; kx++)
          xv[ci * 9 + ky * 3 + kx] = xt[ci * XT_CH + (2 * oyl + ky) * XT_PITCH + 2 * ox + kx];
    int oy = 8 * s + oyl;
#pragma unroll
    for (int c = 0; c < 16; c++) {
      float acc = 0.f;
#pragma unroll
      for (int t = 0; t < 27; t++) acc += xv[t] * wt[c * 27 + t];
      float y = acc * mulc[c] + addc[c];
      h1[(size_t)(c * G + bg) * 12544 + oy * 112 + ox] = fmaxf(y, 0.f);
    }
  }
}

__global__ __launch_bounds__(256) void stem_dw(
    const float* __restrict__ h1, const float* __restrict__ dw, const float* __restrict__ dwb,
    float* __restrict__ h2) {
  int idx = blockIdx.x * 256 + threadIdx.x;       // ((c*G)+bg)*3136 + q
  int q = idx % N_HW;
  int t = idx / N_HW;
  int bg = t & (G - 1);
  int c = t >> 5;
  int qy = q / 56, qx = q % 56;
  const float* plane = h1 + (size_t)(c * G + bg) * 12544;
  float acc = dwb[c];
#pragma unroll
  for (int ky = 0; ky < 3; ky++) {
    int iy = qy * 2 - 1 + ky;
    if (iy < 0 || iy >= 112) continue;
#pragma unroll
    for (int kx = 0; kx < 3; kx++) {
      int ix = qx * 2 - 1 + kx;
      if (ix < 0 || ix >= 112) continue;
      acc += plane[iy * 112 + ix] * dw[c * 9 + ky * 3 + kx];
    }
  }
  h2[idx] = acc;
}

__global__ __launch_bounds__(256) void stem_pw(
    const float* __restrict__ h2, const float* __restrict__ w2, const float* __restrict__ b2,
    const float* __restrict__ g, const float* __restrict__ bb,
    const float* __restrict__ m, const float* __restrict__ v,
    float* __restrict__ H0) {
  int idx = blockIdx.x * 256 + threadIdx.x;       // ((o*G)+bg)*3136 + q
  int q = idx % N_HW;
  int t = idx / N_HW;
  int bg = t & (G - 1);
  int o = t >> 5;
  float acc = b2[o];
#pragma unroll
  for (int c = 0; c < 16; c++) acc += w2[o * 16 + c] * h2[(size_t)(c * G + bg) * N_HW + q];
  float y = (acc - m[o]) * (g[o] * rsqrtf(v[o] + EPS)) + bb[o];
  H0[idx] = y;
}

// ------- fused instance-norm stats + norm + relu + depthwise 3x3 (pad 1) -------
template <typename T>
__global__ __launch_bounds__(256) void dw_fused(
    const T* __restrict__ base, const float* __restrict__ cdw,
    const float* __restrict__ in_g, const float* __restrict__ in_b,
    u16* __restrict__ XA, int cdwoff) {
  __shared__ float sm[58 * 58];
  __shared__ float wred[8];
  int blk = blockIdx.x;            // cl*G + bg
  int cl = blk >> 5;
  int c = cdwoff + cl;
  int tid = threadIdx.x;

  // halo-only zero init (rows 0,57; cols 0,57 of rows 1..56)
  if (tid < 58) { sm[tid] = 0.f; sm[57 * 58 + tid] = 0.f; }
  if (tid >= 64 && tid < 120) { int r = tid - 63; sm[r * 58] = 0.f; sm[r * 58 + 57] = 0.f; }

  const T* row = base + (size_t)blk * N_HW;
  float s = 0.f, s2 = 0.f;
  for (int i = tid; i < 392; i += 256) {
    float vals[8];
    if constexpr (sizeof(T) == 2) {
      uint4 u = *(const uint4*)((const u16*)row + i * 8);
      vals[0] = blo(u.x); vals[1] = bhi(u.x);
      vals[2] = blo(u.y); vals[3] = bhi(u.y);
      vals[4] = blo(u.z); vals[5] = bhi(u.z);
      vals[6] = blo(u.w); vals[7] = bhi(u.w);
    } else {
      float4 v0 = *(const float4*)((const float*)row + i * 8);
      float4 v1 = *(const float4*)((const float*)row + i * 8 + 4);
      vals[0] = v0.x; vals[1] = v0.y; vals[2] = v0.z; vals[3] = v0.w;
      vals[4] = v1.x; vals[5] = v1.y; vals[6] = v1.z; vals[7] = v1.w;
    }
    int p = i * 8;
    int y = p / 56, x = p - y * 56;
    float* d = &sm[(y + 1) * 58 + x + 1];
#pragma unroll
    for (int e = 0; e < 8; e++) {
      d[e] = vals[e];
      s += vals[e];
      s2 += vals[e] * vals[e];
    }
  }
#pragma unroll
  for (int o = 32; o > 0; o >>= 1) {
    s += __shfl_down(s, o);
    s2 += __shfl_down(s2, o);
  }
  if ((tid & 63) == 0) { wred[(tid >> 6) * 2] = s; wred[(tid >> 6) * 2 + 1] = s2; }
  __syncthreads();
  float ts = (wred[0] + wred[2]) + (wred[4] + wred[6]);
  float tq = (wred[1] + wred[3]) + (wred[5] + wred[7]);
  float mean = ts * (1.f / N_HW);
  float var = fmaxf(tq * (1.f / N_HW) - mean * mean, 0.f);
  float sc = in_g[c] * rsqrtf(var + EPS);
  float sh = in_b[c] - mean * sc;

  for (int i = tid; i < N_HW; i += 256) {
    int y = i / 56, x = i - y * 56;
    int pos = (y + 1) * 58 + x + 1;
    sm[pos] = fmaxf(sm[pos] * sc + sh, 0.f);
  }
  __syncthreads();

  float w0 = cdw[c * 9 + 0], w1 = cdw[c * 9 + 1], w2 = cdw[c * 9 + 2];
  float w3 = cdw[c * 9 + 3], w4 = cdw[c * 9 + 4], w5 = cdw[c * 9 + 5];
  float w6 = cdw[c * 9 + 6], w7 = cdw[c * 9 + 7], w8 = cdw[c * 9 + 8];
  u16* outp = XA + (size_t)blk * N_HW;
  for (int pp = tid; pp < N_HW / 2; pp += 256) {   // pairs (56 even -> same row)
    int p = pp * 2;
    int y = p / 56, x = p - y * 56;
    const float* p0 = &sm[y * 58 + x];
    float a0 = p0[0] * w0 + p0[1] * w1 + p0[2] * w2
             + p0[58] * w3 + p0[59] * w4 + p0[60] * w5
             + p0[116] * w6 + p0[117] * w7 + p0[118] * w8;
    float a1 = p0[1] * w0 + p0[2] * w1 + p0[3] * w2
             + p0[59] * w3 + p0[60] * w4 + p0[61] * w5
             + p0[117] * w6 + p0[118] * w7 + p0[119] * w8;
    unsigned pk = (unsigned)f2b(a0) | ((unsigned)f2b(a1) << 16);
    *(unsigned*)&outp[p] = pk;
  }
}

// ---------------- MFMA GEMM: C[192][NG] = A[192][K] @ B[K][NG] ----------------
// r8 known-good structure: N-tile 64, 4 waves 2x2, wave tile 96x32,
// register-staged double-buffer, one barrier per K-tile, XOR-16 swizzled B.
// MODE 0: store bf16 C.  MODE 1 (L3): per-row stats atomics + f32 patch spill.
template <int MODE>
__global__ __launch_bounds__(256) void gemm_mfma(
    const u16* __restrict__ A, const u16* __restrict__ B, u16* __restrict__ C,
    float* __restrict__ statS, float* __restrict__ statQ, float* __restrict__ patchf,
    int K) {
  __shared__ u16 As[2][192][40];   // pitch 80 B
  __shared__ u16 Bs[2][32][64];    // pitch 128 B, XOR-16 column swizzle
  int n0 = blockIdx.x * 64;
  int tid = threadIdx.x;
  int wave = tid >> 6, lane = tid & 63;
  int wm = wave >> 1, wn = wave & 1;
  int lg = lane >> 4, li = lane & 15;
  floatx4 acc[6][2] = {};

  int ar = tid >> 2, ak = (tid & 3) * 8;
  int bk = tid >> 3, bn = (tid & 7) * 8;
  int bnx = bn ^ ((bk >> 3) << 4);
  const u16* Ag = A + (size_t)ar * DIMC + ak;
  const u16* Bg = B + (size_t)bk * NG + n0 + bn;

  int nt = K / 32;
  *(uint4*)&As[0][ar][ak]       = *(const uint4*)(Ag);
  *(uint4*)&As[0][ar + 64][ak]  = *(const uint4*)(Ag + (size_t)64 * DIMC);
  *(uint4*)&As[0][ar + 128][ak] = *(const uint4*)(Ag + (size_t)128 * DIMC);
  *(uint4*)&Bs[0][bk][bnx]      = *(const uint4*)(Bg);
  __syncthreads();

  int cur = 0;
  for (int t = 0; t < nt; t++) {
    uint4 ra0, ra1, ra2, rb;
    bool pf = (t + 1 < nt);
    if (pf) {
      const u16* ag = Ag + (size_t)(t + 1) * 32;
      ra0 = *(const uint4*)(ag);
      ra1 = *(const uint4*)(ag + (size_t)64 * DIMC);
      ra2 = *(const uint4*)(ag + (size_t)128 * DIMC);
      rb  = *(const uint4*)(Bg + (size_t)(t + 1) * 32 * NG);
    }
    short8 aF[6];
#pragma unroll
    for (int mi = 0; mi < 6; mi++)
      aF[mi] = *(const short8*)&As[cur][wm * 96 + mi * 16 + li][lg * 8];
#pragma unroll
    for (int ni = 0; ni < 2; ni++) {
      int colx = ((wn * 32 + ni * 16) ^ (lg << 4)) + li;
      short8 bF;
#pragma unroll
      for (int e = 0; e < 8; e++) bF[e] = (short)Bs[cur][lg * 8 + e][colx];
#pragma unroll
      for (int mi = 0; mi < 6; mi++)
        acc[mi][ni] = __builtin_amdgcn_mfma_f32_16x16x32_bf16(aF[mi], bF, acc[mi][ni], 0, 0, 0);
    }
    if (pf) {
      *(uint4*)&As[cur ^ 1][ar][ak]       = ra0;
      *(uint4*)&As[cur ^ 1][ar + 64][ak]  = ra1;
      *(uint4*)&As[cur ^ 1][ar + 128][ak] = ra2;
      *(uint4*)&Bs[cur ^ 1][bk][bnx]      = rb;
    }
    __syncthreads();
    cur ^= 1;
  }

  if constexpr (MODE == 0) {
#pragma unroll
    for (int mi = 0; mi < 6; mi++) {
#pragma unroll
      for (int ni = 0; ni < 2; ni++) {
        int row = wm * 96 + mi * 16 + lg * 4;   // C/D: col=lane&15, row=lg*4+r
        int col = n0 + wn * 32 + ni * 16 + li;
        u16* cp = C + (size_t)row * NG + col;
#pragma unroll
        for (int r = 0; r < 4; r++) cp[(size_t)r * NG] = f2b(acc[mi][ni][r]);
      }
    }
  } else {
    int bg = blockIdx.x / NTILE;
    int tile = blockIdx.x % NTILE;
    // per-row partial sums over this block's 64 columns
#pragma unroll
    for (int mi = 0; mi < 6; mi++) {
#pragma unroll
      for (int r = 0; r < 4; r++) {
        float v0 = acc[mi][0][r], v1 = acc[mi][1][r];
        float s = v0 + v1;
        float q = v0 * v0 + v1 * v1;
#pragma unroll
        for (int msk = 1; msk < 16; msk <<= 1) {
          s += __shfl_xor(s, msk);
          q += __shfl_xor(q, msk);
        }
        if (li == 0) {
          int row = wm * 96 + mi * 16 + lg * 4 + r;
          atomicAdd(&statS[row * 32 + bg], s);
          atomicAdd(&statQ[row * 32 + bg], q);
        }
      }
    }
    // f32 spill of the readout-patch tiles (hw in [1408,1599] -> tiles 22..24)
    if (tile >= 22 && tile <= 24) {
#pragma unroll
      for (int mi = 0; mi < 6; mi++) {
#pragma unroll
        for (int ni = 0; ni < 2; ni++) {
          int row = wm * 96 + mi * 16 + lg * 4;
          int pc = (tile - 22) * 64 + wn * 32 + ni * 16 + li;
#pragma unroll
          for (int r = 0; r < 4; r++)
            patchf[((size_t)(row + r) * 32 + bg) * 192 + pc] = acc[mi][ni][r];
        }
      }
    }
  }
}

// ------- head: layer-4 norm + dwconv on patch, stats from GEMM epilogue -------
__global__ __launch_bounds__(256) void head_m4(
    const float* __restrict__ statS, const float* __restrict__ statQ,
    const float* __restrict__ patchf,
    const float* __restrict__ in_g, const float* __restrict__ in_b,
    const float* __restrict__ cdw, float* __restrict__ m4, float* __restrict__ meanH) {
  int idx = blockIdx.x * 256 + threadIdx.x;   // cl*32 + bg
  if (idx >= 192 * 32) return;
  int cl = idx >> 5;
  int c = 608 + cl;
  float mean = statS[idx] * (1.f / N_HW);
  float var = fmaxf(statQ[idx] * (1.f / N_HW) - mean * mean, 0.f);
  float sc = in_g[c] * rsqrtf(var + EPS);
  float sh = in_b[c] - mean * sc;
  const float* pf = patchf + (size_t)idx * 192;
  float val[4][4];
#pragma unroll
  for (int dy = 0; dy < 4; dy++)
#pragma unroll
    for (int dx = 0; dx < 4; dx++) {
      int hw = (25 + dy) * 56 + 25 + dx;
      float v = pf[((hw >> 6) - 22) * 64 + (hw & 63)];
      val[dy][dx] = fmaxf(v * sc + sh, 0.f);
    }
  const float* w = cdw + c * 9;
  float acc = 0.f;
#pragma unroll
  for (int oy = 1; oy < 3; oy++)
#pragma unroll
    for (int ox = 1; ox < 3; ox++)
#pragma unroll
      for (int ky = 0; ky < 3; ky++)
#pragma unroll
        for (int kx = 0; kx < 3; kx++)
          acc += val[oy + ky - 1][ox + kx - 1] * w[ky * 3 + kx];
  m4[idx] = acc * 0.25f;
  float mh = 0.f;
#pragma unroll
  for (int dy = 0; dy < 2; dy++)
#pragma unroll
    for (int dx = 0; dx < 2; dx++) {
      int hw = (26 + dy) * 56 + 26 + dx;
      mh += pf[((hw >> 6) - 22) * 64 + (hw & 63)];
    }
  meanH[idx] = mh * 0.25f;
}

__global__ __launch_bounds__(256) void head_mix(
    const float* __restrict__ gw, const float* __restrict__ m4, const float* __restrict__ meanH,
    float* __restrict__ out_pre) {
  int idx = blockIdx.x * 256 + threadIdx.x;   // bg*192 + j
  if (idx >= G * 192) return;
  int j = idx % 192;
  int bg = idx / 192;
  float acc = meanH[j * G + bg];
  const float* grow = gw + (size_t)(608 + j) * DIMC + 608;
  for (int c = 0; c < 192; c++) acc += grow[c] * m4[c * G + bg];
  out_pre[idx] = acc;
}

__global__ __launch_bounds__(256) void head_fc(
    const float* __restrict__ out_pre, const float* __restrict__ fc_w,
    const float* __restrict__ fc_b, float* __restrict__ outg) {
  int idx = blockIdx.x * 256 + threadIdx.x;   // bg*1000 + t
  if (idx >= G * 1000) return;
  int t = idx % 1000;
  int bg = idx / 1000;
  float acc = fc_b[t];
  const float* wr = fc_w + (size_t)t * 192;
  const float* hr = out_pre + (size_t)bg * 192;
  for (int j = 0; j < 192; j++) acc += wr[j] * hr[j];
  outg[idx] = acc;
}

extern "C" void kernel_launch(void* const* d_in, const int* in_sizes, int n_in,
                              void* d_out, int out_size, void* d_ws, size_t ws_size,
                              hipStream_t stream) {
  const float* x      = (const float*)d_in[0];
  const float* ds_w1  = (const float*)d_in[1];
  const float* ds_b1  = (const float*)d_in[2];
  const float* bn1_g  = (const float*)d_in[3];
  const float* bn1_b  = (const float*)d_in[4];
  const float* bn1_m  = (const float*)d_in[5];
  const float* bn1_v  = (const float*)d_in[6];
  const float* ds_dw  = (const float*)d_in[7];
  const float* ds_dwb = (const float*)d_in[8];
  const float* ds_w2  = (const float*)d_in[9];
  const float* ds_b2  = (const float*)d_in[10];
  const float* bn2_g  = (const float*)d_in[11];
  const float* bn2_b  = (const float*)d_in[12];
  const float* bn2_m  = (const float*)d_in[13];
  const float* bn2_v  = (const float*)d_in[14];
  const float* cdw    = (const float*)d_in[15];
  const float* gw     = (const float*)d_in[16];
  const float* in_g   = (const float*)d_in[17];
  const float* in_b   = (const float*)d_in[18];
  const float* fc_w   = (const float*)d_in[19];
  const float* fc_b   = (const float*)d_in[20];
  float* out = (float*)d_out;
  char* ws = (char*)d_ws;

  if (ws_size < NEED) return;

  u16*   XAc    = (u16*)(ws + XA_OFF);
  float* H0     = (float*)(ws + H0_OFF);
  u16*   blockb = (u16*)(ws + BLK_OFF);
  u16*   gwb    = (u16*)(ws + GWB_OFF);
  float* statS  = (float*)(ws + STS_OFF);
  float* statQ  = (float*)(ws + STQ_OFF);
  float* patchf = (float*)(ws + PAT_OFF);
  float* m4     = (float*)(ws + M4_OFF);
  float* meanH  = (float*)(ws + MH_OFF);
  float* opre   = (float*)(ws + OP_OFF);
  float* h1     = (float*)(ws + BLK_OFF);           // stem temps alias blockb
  float* h2     = h1 + (size_t)16 * G * 12544;

  gw2bf<<<625, 256, 0, stream>>>(gw, gwb);
  zero_stats<<<48, 256, 0, stream>>>(statS);        // statS+statQ contiguous

  static const int CDWOFF[4] = {0, 32, 224, 416};   // dw layer channel base
  static const int SZ[4]     = {32, 192, 192, 192};
  static const int RA[4]     = {32, 224, 416, 608}; // gemm output channel base
  static const int KK[4]     = {32, 224, 416, 608};

  stem_conv1<<<14 * G, 256, 0, stream>>>(
      x, ds_w1, ds_b1, bn1_g, bn1_b, bn1_m, bn1_v, h1);
  stem_dw<<<16 * G * N_HW / 256, 256, 0, stream>>>(h1, ds_dw, ds_dwb, h2);
  stem_pw<<<32 * G * N_HW / 256, 256, 0, stream>>>(
      h2, ds_w2, ds_b2, bn2_g, bn2_b, bn2_m, bn2_v, H0);

  for (int i = 0; i < 4; i++) {
    if (i == 0)
      dw_fused<float><<<SZ[i] * G, 256, 0, stream>>>(
          H0, cdw, in_g, in_b, XAc + (size_t)CDWOFF[i] * NG, CDWOFF[i]);
    else
      dw_fused<u16><<<SZ[i] * G, 256, 0, stream>>>(
          blockb, cdw, in_g, in_b, XAc + (size_t)CDWOFF[i] * NG, CDWOFF[i]);
    if (i < 3)
      gemm_mfma<0><<<NG / 64, 256, 0, stream>>>(
          gwb + (size_t)RA[i] * DIMC, XAc, blockb, nullptr, nullptr, nullptr, KK[i]);
    else
      gemm_mfma<1><<<NG / 64, 256, 0, stream>>>(
          gwb + (size_t)RA[i] * DIMC, XAc, nullptr, statS, statQ, patchf, KK[i]);
  }

  head_m4<<<24, 256, 0, stream>>>(statS, statQ, patchf, in_g, in_b, cdw, m4, meanH);
  head_mix<<<(G * 192 + 255) / 256, 256, 0, stream>>>(gw, m4, meanH, opre);
  head_fc<<<(G * 1000 + 255) / 256, 256, 0, stream>>>(opre, fc_w, fc_b, out);
}

// Round 12
// 390.766 us; speedup vs baseline: 2.6676x; 1.0036x over previous
//
#include <hip/hip_runtime.h>
#include <stddef.h>

#define EPS 1e-5f
#define N_HW 3136              // 56*56
#define G 32                   // full batch, single pass
#define NG (G * N_HW)          // 100352 = GEMM N dimension
#define DIMC 800
#define NTILE 49               // 3136/64: 64-col tiles per image

typedef unsigned short u16;
typedef __attribute__((ext_vector_type(8))) short short8;
typedef __attribute__((ext_vector_type(4))) float floatx4;

__device__ __forceinline__ u16 f2b(float f) {
  unsigned u = __float_as_uint(f);
  u += 0x7FFFu + ((u >> 16) & 1u);        // round-to-nearest-even
  return (u16)(u >> 16);
}
__device__ __forceinline__ float blo(unsigned u) { return __uint_as_float(u << 16); }
__device__ __forceinline__ float bhi(unsigned u) { return __uint_as_float(u & 0xFFFF0000u); }

// ---------------- ws layout (bytes) ----------------
static const size_t XA_OFF  = 0;
static const size_t H0_OFF  = 122028032ull;
static const size_t BLK_OFF = 134873088ull;
static const size_t GWB_OFF = 173408256ull;
static const size_t STS_OFF = 174688256ull;
static const size_t STQ_OFF = 174712832ull;
static const size_t PAT_OFF = 174737408ull;
static const size_t M4_OFF  = 179456000ull;
static const size_t MH_OFF  = M4_OFF + 6144 * 4;
static const size_t OP_OFF  = MH_OFF + 6144 * 4;
static const size_t NEED    = OP_OFF + 6144 * 4;   // ~179.5 MB

// ---------------- small utility kernels ----------------
__global__ __launch_bounds__(256) void gw2bf(const float* __restrict__ gw, u16* __restrict__ gwb) {
  int i = (blockIdx.x * 256 + threadIdx.x) * 4;   // 640000 elems, 625 blocks
  float4 v = *(const float4*)(gw + i);
  gwb[i + 0] = f2b(v.x); gwb[i + 1] = f2b(v.y);
  gwb[i + 2] = f2b(v.z); gwb[i + 3] = f2b(v.w);
}

__global__ __launch_bounds__(256) void zero_stats(float* __restrict__ p) {
  p[blockIdx.x * 256 + threadIdx.x] = 0.f;        // 12288 floats, 48 blocks
}

// ---------------- stem conv1: LDS-tiled, all 16 ch per block ----------------
#define XT_PITCH 226
#define XT_CH (17 * XT_PITCH)          // 3842
__global__ __launch_bounds__(256) void stem_conv1(
    const float* __restrict__ xg, const float* __restrict__ w, const float* __restrict__ b1,
    const float* __restrict__ g, const float* __restrict__ bb,
    const float* __restrict__ m, const float* __restrict__ v,
    float* __restrict__ h1) {
  __shared__ float xt[3 * XT_CH];      // 46.1 KB
  __shared__ float wt[16 * 27];
  __shared__ float mulc[16], addc[16];
  int blk = blockIdx.x;                // s + 14*bg
  int s = blk % 14;
  int bg = blk / 14;
  int tid = threadIdx.x;

  for (int e = tid; e < 432; e += 256) wt[e] = w[e];
  if (tid < 16) {
    float A = g[tid] * rsqrtf(v[tid] + EPS);
    mulc[tid] = A;
    addc[tid] = (b1[tid] - m[tid]) * A + bb[tid];
  }
  int iy0 = 16 * s - 1;
  for (int e = tid; e < 3 * XT_CH; e += 256) {
    int ci = e / XT_CH;
    int rem = e - ci * XT_CH;
    int r = rem / XT_PITCH;
    int cc = rem - r * XT_PITCH;
    int iy = iy0 + r, ix = cc - 1;
    float val = 0.f;
    if (iy >= 0 && iy < 224 && ix >= 0 && ix < 224)
      val = xg[((size_t)(bg * 3 + ci)) * 224 * 224 + iy * 224 + ix];
    xt[e] = val;
  }
  __syncthreads();

  for (int p = tid; p < 8 * 112; p += 256) {
    int oyl = p / 112, ox = p - oyl * 112;
    float xv[27];
#pragma unroll
    for (int ci = 0; ci < 3; ci++)
#pragma unroll
      for (int ky = 0; ky < 3; ky++)
#pragma unroll
        for (int kx = 0; kx < 3; kx++)
          xv[ci * 9 + ky * 3 + kx] = xt[ci * XT_CH + (2 * oyl + ky) * XT_PITCH + 2 * ox + kx];
    int oy = 8 * s + oyl;
#pragma unroll
    for (int c = 0; c < 16; c++) {
      float acc = 0.f;
#pragma unroll
      for (int t = 0; t < 27; t++) acc += xv[t] * wt[c * 27 + t];
      float y = acc * mulc[c] + addc[c];
      h1[(size_t)(c * G + bg) * 12544 + oy * 112 + ox] = fmaxf(y, 0.f);
    }
  }
}

__global__ __launch_bounds__(256) void stem_dw(
    const float* __restrict__ h1, const float* __restrict__ dw, const float* __restrict__ dwb,
    float* __restrict__ h2) {
  int idx = blockIdx.x * 256 + threadIdx.x;       // ((c*G)+bg)*3136 + q
  int q = idx % N_HW;
  int t = idx / N_HW;
  int bg = t & (G - 1);
  int c = t >> 5;
  int qy = q / 56, qx = q % 56;
  const float* plane = h1 + (size_t)(c * G + bg) * 12544;
  float acc = dwb[c];
#pragma unroll
  for (int ky = 0; ky < 3; ky++) {
    int iy = qy * 2 - 1 + ky;
    if (iy < 0 || iy >= 112) continue;
#pragma unroll
    for (int kx = 0; kx < 3; kx++) {
      int ix = qx * 2 - 1 + kx;
      if (ix < 0 || ix >= 112) continue;
      acc += plane[iy * 112 + ix] * dw[c * 9 + ky * 3 + kx];
    }
  }
  h2[idx] = acc;
}

__global__ __launch_bounds__(256) void stem_pw(
    const float* __restrict__ h2, const float* __restrict__ w2, const float* __restrict__ b2,
    const float* __restrict__ g, const float* __restrict__ bb,
    const float* __restrict__ m, const float* __restrict__ v,
    float* __restrict__ H0) {
  int idx = blockIdx.x * 256 + threadIdx.x;       // ((o*G)+bg)*3136 + q
  int q = idx % N_HW;
  int t = idx / N_HW;
  int bg = t & (G - 1);
  int o = t >> 5;
  float acc = b2[o];
#pragma unroll
  for (int c = 0; c < 16; c++) acc += w2[o * 16 + c] * h2[(size_t)(c * G + bg) * N_HW + q];
  float y = (acc - m[o]) * (g[o] * rsqrtf(v[o] + EPS)) + bb[o];
  H0[idx] = y;
}

// ------- fused instance-norm stats + norm + relu + depthwise 3x3 (pad 1) -------
template <typename T>
__global__ __launch_bounds__(256) void dw_fused(
    const T* __restrict__ base, const float* __restrict__ cdw,
    const float* __restrict__ in_g, const float* __restrict__ in_b,
    u16* __restrict__ XA, int cdwoff) {
  __shared__ float sm[58 * 58];
  __shared__ float wred[8];
  int blk = blockIdx.x;            // cl*G + bg
  int cl = blk >> 5;
  int c = cdwoff + cl;
  int tid = threadIdx.x;

  // halo-only zero init (rows 0,57; cols 0,57 of rows 1..56)
  if (tid < 58) { sm[tid] = 0.f; sm[57 * 58 + tid] = 0.f; }
  if (tid >= 64 && tid < 120) { int r = tid - 63; sm[r * 58] = 0.f; sm[r * 58 + 57] = 0.f; }

  const T* row = base + (size_t)blk * N_HW;
  float s = 0.f, s2 = 0.f;
  for (int i = tid; i < 392; i += 256) {
    float vals[8];
    if constexpr (sizeof(T) == 2) {
      uint4 u = *(const uint4*)((const u16*)row + i * 8);
      vals[0] = blo(u.x); vals[1] = bhi(u.x);
      vals[2] = blo(u.y); vals[3] = bhi(u.y);
      vals[4] = blo(u.z); vals[5] = bhi(u.z);
      vals[6] = blo(u.w); vals[7] = bhi(u.w);
    } else {
      float4 v0 = *(const float4*)((const float*)row + i * 8);
      float4 v1 = *(const float4*)((const float*)row + i * 8 + 4);
      vals[0] = v0.x; vals[1] = v0.y; vals[2] = v0.z; vals[3] = v0.w;
      vals[4] = v1.x; vals[5] = v1.y; vals[6] = v1.z; vals[7] = v1.w;
    }
    int p = i * 8;
    int y = p / 56, x = p - y * 56;
    float* d = &sm[(y + 1) * 58 + x + 1];
#pragma unroll
    for (int e = 0; e < 8; e++) {
      d[e] = vals[e];
      s += vals[e];
      s2 += vals[e] * vals[e];
    }
  }
#pragma unroll
  for (int o = 32; o > 0; o >>= 1) {
    s += __shfl_down(s, o);
    s2 += __shfl_down(s2, o);
  }
  if ((tid & 63) == 0) { wred[(tid >> 6) * 2] = s; wred[(tid >> 6) * 2 + 1] = s2; }
  __syncthreads();
  float ts = (wred[0] + wred[2]) + (wred[4] + wred[6]);
  float tq = (wred[1] + wred[3]) + (wred[5] + wred[7]);
  float mean = ts * (1.f / N_HW);
  float var = fmaxf(tq * (1.f / N_HW) - mean * mean, 0.f);
  float sc = in_g[c] * rsqrtf(var + EPS);
  float sh = in_b[c] - mean * sc;

  for (int i = tid; i < N_HW; i += 256) {
    int y = i / 56, x = i - y * 56;
    int pos = (y + 1) * 58 + x + 1;
    sm[pos] = fmaxf(sm[pos] * sc + sh, 0.f);
  }
  __syncthreads();

  float w0 = cdw[c * 9 + 0], w1 = cdw[c * 9 + 1], w2 = cdw[c * 9 + 2];
  float w3 = cdw[c * 9 + 3], w4 = cdw[c * 9 + 4], w5 = cdw[c * 9 + 5];
  float w6 = cdw[c * 9 + 6], w7 = cdw[c * 9 + 7], w8 = cdw[c * 9 + 8];
  u16* outp = XA + (size_t)blk * N_HW;
  for (int pp = tid; pp < N_HW / 2; pp += 256) {   // pairs (56 even -> same row)
    int p = pp * 2;
    int y = p / 56, x = p - y * 56;
    const float* p0 = &sm[y * 58 + x];
    float a0 = p0[0] * w0 + p0[1] * w1 + p0[2] * w2
             + p0[58] * w3 + p0[59] * w4 + p0[60] * w5
             + p0[116] * w6 + p0[117] * w7 + p0[118] * w8;
    float a1 = p0[1] * w0 + p0[2] * w1 + p0[3] * w2
             + p0[59] * w3 + p0[60] * w4 + p0[61] * w5
             + p0[117] * w6 + p0[118] * w7 + p0[119] * w8;
    unsigned pk = (unsigned)f2b(a0) | ((unsigned)f2b(a1) << 16);
    *(unsigned*)&outp[p] = pk;
  }
}

// ---------------- MFMA GEMM: C[192][NG] = A[192][K] @ B[K][NG] ----------------
// SINGLE-buffered LDS (19.4 KB -> ~6 blocks/CU resident, TLP latency hiding),
// 2 barriers per K-tile, registers staged one tile ahead:
//   write(t) -> barrier -> issue loads(t+1) -> compute(t) -> barrier.
// MODE 0: store bf16 C.  MODE 1 (L3): per-row stats atomics + f32 patch spill.
template <int MODE>
__global__ __launch_bounds__(256) void gemm_mfma(
    const u16* __restrict__ A, const u16* __restrict__ B, u16* __restrict__ C,
    float* __restrict__ statS, float* __restrict__ statQ, float* __restrict__ patchf,
    int K) {
  __shared__ u16 As[192][40];   // pitch 80 B, 15.36 KB
  __shared__ u16 Bs[32][64];    // pitch 128 B, XOR-16 column swizzle, 4 KB
  int n0 = blockIdx.x * 64;
  int tid = threadIdx.x;
  int wave = tid >> 6, lane = tid & 63;
  int wm = wave >> 1, wn = wave & 1;
  int lg = lane >> 4, li = lane & 15;
  floatx4 acc[6][2] = {};

  int ar = tid >> 2, ak = (tid & 3) * 8;
  int bk = tid >> 3, bn = (tid & 7) * 8;
  int bnx = bn ^ ((bk >> 3) << 4);
  const u16* Ag = A + (size_t)ar * DIMC + ak;
  const u16* Bg = B + (size_t)bk * NG + n0 + bn;

  int nt = K / 32;
  // stage tile 0 into registers
  uint4 ra0 = *(const uint4*)(Ag);
  uint4 ra1 = *(const uint4*)(Ag + (size_t)64 * DIMC);
  uint4 ra2 = *(const uint4*)(Ag + (size_t)128 * DIMC);
  uint4 rb  = *(const uint4*)(Bg);

  for (int t = 0; t < nt; t++) {
    // write staged regs -> LDS (vmcnt waits only on loads issued last iter)
    *(uint4*)&As[ar][ak]       = ra0;
    *(uint4*)&As[ar + 64][ak]  = ra1;
    *(uint4*)&As[ar + 128][ak] = ra2;
    *(uint4*)&Bs[bk][bnx]      = rb;
    __syncthreads();
    if (t + 1 < nt) {                           // issue next-tile loads now;
      const u16* ag = Ag + (size_t)(t + 1) * 32; // they fly during compute(t)
      ra0 = *(const uint4*)(ag);
      ra1 = *(const uint4*)(ag + (size_t)64 * DIMC);
      ra2 = *(const uint4*)(ag + (size_t)128 * DIMC);
      rb  = *(const uint4*)(Bg + (size_t)(t + 1) * 32 * NG);
    }
    short8 aF[6];
#pragma unroll
    for (int mi = 0; mi < 6; mi++)
      aF[mi] = *(const short8*)&As[wm * 96 + mi * 16 + li][lg * 8];
#pragma unroll
    for (int ni = 0; ni < 2; ni++) {
      int colx = ((wn * 32 + ni * 16) ^ (lg << 4)) + li;
      short8 bF;
#pragma unroll
      for (int e = 0; e < 8; e++) bF[e] = (short)Bs[lg * 8 + e][colx];
#pragma unroll
      for (int mi = 0; mi < 6; mi++)
        acc[mi][ni] = __builtin_amdgcn_mfma_f32_16x16x32_bf16(aF[mi], bF, acc[mi][ni], 0, 0, 0);
    }
    __syncthreads();                            // all reads done before next write
  }

  if constexpr (MODE == 0) {
#pragma unroll
    for (int mi = 0; mi < 6; mi++) {
#pragma unroll
      for (int ni = 0; ni < 2; ni++) {
        int row = wm * 96 + mi * 16 + lg * 4;   // C/D: col=lane&15, row=lg*4+r
        int col = n0 + wn * 32 + ni * 16 + li;
        u16* cp = C + (size_t)row * NG + col;
#pragma unroll
        for (int r = 0; r < 4; r++) cp[(size_t)r * NG] = f2b(acc[mi][ni][r]);
      }
    }
  } else {
    int bg = blockIdx.x / NTILE;
    int tile = blockIdx.x % NTILE;
#pragma unroll
    for (int mi = 0; mi < 6; mi++) {
#pragma unroll
      for (int r = 0; r < 4; r++) {
        float v0 = acc[mi][0][r], v1 = acc[mi][1][r];
        float s = v0 + v1;
        float q = v0 * v0 + v1 * v1;
#pragma unroll
        for (int msk = 1; msk < 16; msk <<= 1) {
          s += __shfl_xor(s, msk);
          q += __shfl_xor(q, msk);
        }
        if (li == 0) {
          int row = wm * 96 + mi * 16 + lg * 4 + r;
          atomicAdd(&statS[row * 32 + bg], s);
          atomicAdd(&statQ[row * 32 + bg], q);
        }
      }
    }
    if (tile >= 22 && tile <= 24) {
#pragma unroll
      for (int mi = 0; mi < 6; mi++) {
#pragma unroll
        for (int ni = 0; ni < 2; ni++) {
          int row = wm * 96 + mi * 16 + lg * 4;
          int pc = (tile - 22) * 64 + wn * 32 + ni * 16 + li;
#pragma unroll
          for (int r = 0; r < 4; r++)
            patchf[((size_t)(row + r) * 32 + bg) * 192 + pc] = acc[mi][ni][r];
        }
      }
    }
  }
}

// ------- head: layer-4 norm + dwconv on patch, stats from GEMM epilogue -------
__global__ __launch_bounds__(256) void head_m4(
    const float* __restrict__ statS, const float* __restrict__ statQ,
    const float* __restrict__ patchf,
    const float* __restrict__ in_g, const float* __restrict__ in_b,
    const float* __restrict__ cdw, float* __restrict__ m4, float* __restrict__ meanH) {
  int idx = blockIdx.x * 256 + threadIdx.x;   // cl*32 + bg
  if (idx >= 192 * 32) return;
  int cl = idx >> 5;
  int c = 608 + cl;
  float mean = statS[idx] * (1.f / N_HW);
  float var = fmaxf(statQ[idx] * (1.f / N_HW) - mean * mean, 0.f);
  float sc = in_g[c] * rsqrtf(var + EPS);
  float sh = in_b[c] - mean * sc;
  const float* pf = patchf + (size_t)idx * 192;
  float val[4][4];
#pragma unroll
  for (int dy = 0; dy < 4; dy++)
#pragma unroll
    for (int dx = 0; dx < 4; dx++) {
      int hw = (25 + dy) * 56 + 25 + dx;
      float v = pf[((hw >> 6) - 22) * 64 + (hw & 63)];
      val[dy][dx] = fmaxf(v * sc + sh, 0.f);
    }
  const float* w = cdw + c * 9;
  float acc = 0.f;
#pragma unroll
  for (int oy = 1; oy < 3; oy++)
#pragma unroll
    for (int ox = 1; ox < 3; ox++)
#pragma unroll
      for (int ky = 0; ky < 3; ky++)
#pragma unroll
        for (int kx = 0; kx < 3; kx++)
          acc += val[oy + ky - 1][ox + kx - 1] * w[ky * 3 + kx];
  m4[idx] = acc * 0.25f;
  float mh = 0.f;
#pragma unroll
  for (int dy = 0; dy < 2; dy++)
#pragma unroll
    for (int dx = 0; dx < 2; dx++) {
      int hw = (26 + dy) * 56 + 26 + dx;
      mh += pf[((hw >> 6) - 22) * 64 + (hw & 63)];
    }
  meanH[idx] = mh * 0.25f;
}

__global__ __launch_bounds__(256) void head_mix(
    const float* __restrict__ gw, const float* __restrict__ m4, const float* __restrict__ meanH,
    float* __restrict__ out_pre) {
  int idx = blockIdx.x * 256 + threadIdx.x;   // bg*192 + j
  if (idx >= G * 192) return;
  int j = idx % 192;
  int bg = idx / 192;
  float acc = meanH[j * G + bg];
  const float* grow = gw + (size_t)(608 + j) * DIMC + 608;
  for (int c = 0; c < 192; c++) acc += grow[c] * m4[c * G + bg];
  out_pre[idx] = acc;
}

__global__ __launch_bounds__(256) void head_fc(
    const float* __restrict__ out_pre, const float* __restrict__ fc_w,
    const float* __restrict__ fc_b, float* __restrict__ outg) {
  int idx = blockIdx.x * 256 + threadIdx.x;   // bg*1000 + t
  if (idx >= G * 1000) return;
  int t = idx % 1000;
  int bg = idx / 1000;
  float acc = fc_b[t];
  const float* wr = fc_w + (size_t)t * 192;
  const float* hr = out_pre + (size_t)bg * 192;
  for (int j = 0; j < 192; j++) acc += wr[j] * hr[j];
  outg[idx] = acc;
}

extern "C" void kernel_launch(void* const* d_in, const int* in_sizes, int n_in,
                              void* d_out, int out_size, void* d_ws, size_t ws_size,
                              hipStream_t stream) {
  const float* x      = (const float*)d_in[0];
  const float* ds_w1  = (const float*)d_in[1];
  const float* ds_b1  = (const float*)d_in[2];
  const float* bn1_g  = (const float*)d_in[3];
  const float* bn1_b  = (const float*)d_in[4];
  const float* bn1_m  = (const float*)d_in[5];
  const float* bn1_v  = (const float*)d_in[6];
  const float* ds_dw  = (const float*)d_in[7];
  const float* ds_dwb = (const float*)d_in[8];
  const float* ds_w2  = (const float*)d_in[9];
  const float* ds_b2  = (const float*)d_in[10];
  const float* bn2_g  = (const float*)d_in[11];
  const float* bn2_b  = (const float*)d_in[12];
  const float* bn2_m  = (const float*)d_in[13];
  const float* bn2_v  = (const float*)d_in[14];
  const float* cdw    = (const float*)d_in[15];
  const float* gw     = (const float*)d_in[16];
  const float* in_g   = (const float*)d_in[17];
  const float* in_b   = (const float*)d_in[18];
  const float* fc_w   = (const float*)d_in[19];
  const float* fc_b   = (const float*)d_in[20];
  float* out = (float*)d_out;
  char* ws = (char*)d_ws;

  if (ws_size < NEED) return;

  u16*   XAc    = (u16*)(ws + XA_OFF);
  float* H0     = (float*)(ws + H0_OFF);
  u16*   blockb = (u16*)(ws + BLK_OFF);
  u16*   gwb    = (u16*)(ws + GWB_OFF);
  float* statS  = (float*)(ws + STS_OFF);
  float* statQ  = (float*)(ws + STQ_OFF);
  float* patchf = (float*)(ws + PAT_OFF);
  float* m4     = (float*)(ws + M4_OFF);
  float* meanH  = (float*)(ws + MH_OFF);
  float* opre   = (float*)(ws + OP_OFF);
  float* h1     = (float*)(ws + BLK_OFF);           // stem temps alias blockb
  float* h2     = h1 + (size_t)16 * G * 12544;

  gw2bf<<<625, 256, 0, stream>>>(gw, gwb);
  zero_stats<<<48, 256, 0, stream>>>(statS);        // statS+statQ contiguous

  static const int CDWOFF[4] = {0, 32, 224, 416};   // dw layer channel base
  static const int SZ[4]     = {32, 192, 192, 192};
  static const int RA[4]     = {32, 224, 416, 608}; // gemm output channel base
  static const int KK[4]     = {32, 224, 416, 608};

  stem_conv1<<<14 * G, 256, 0, stream>>>(
      x, ds_w1, ds_b1, bn1_g, bn1_b, bn1_m, bn1_v, h1);
  stem_dw<<<16 * G * N_HW / 256, 256, 0, stream>>>(h1, ds_dw, ds_dwb, h2);
  stem_pw<<<32 * G * N_HW / 256, 256, 0, stream>>>(
      h2, ds_w2, ds_b2, bn2_g, bn2_b, bn2_m, bn2_v, H0);

  for (int i = 0; i < 4; i++) {
    if (i == 0)
      dw_fused<float><<<SZ[i] * G, 256, 0, stream>>>(
          H0, cdw, in_g, in_b, XAc + (size_t)CDWOFF[i] * NG, CDWOFF[i]);
    else
      dw_fused<u16><<<SZ[i] * G, 256, 0, stream>>>(
          blockb, cdw, in_g, in_b, XAc + (size_t)CDWOFF[i] * NG, CDWOFF[i]);
    if (i < 3)
      gemm_mfma<0><<<NG / 64, 256, 0, stream>>>(
          gwb + (size_t)RA[i] * DIMC, XAc, blockb, nullptr, nullptr, nullptr, KK[i]);
    else
      gemm_mfma<1><<<NG / 64, 256, 0, stream>>>(
          gwb + (size_t)RA[i] * DIMC, XAc, nullptr, statS, statQ, patchf, KK[i]);
  }

  head_m4<<<24, 256, 0, stream>>>(statS, statQ, patchf, in_g, in_b, cdw, m4, meanH);
  head_mix<<<(G * 192 + 255) / 256, 256, 0, stream>>>(gw, m4, meanH, opre);
  head_fc<<<(G * 1000 + 255) / 256, 256, 0, stream>>>(opre, fc_w, fc_b, out);
}